// Round 15
// baseline (515.123 us; speedup 1.0000x reference)
//
#include <hip/hip_runtime.h>
#include <math.h>
#include <stdint.h>

#define N_NODES 20000
#define M_PAD 20032            // 313 * 64
#define N_EDGES 320000
#define N_GRAPHS 64
#define DIN 128
#define H 256
#define POOL_W 768
#define CHUNK 40               // edges per wave in agg3
#define NCHUNK (N_EDGES / CHUNK)   // 8000 (exact)
#define EDGE_BLOCKS ((N_EDGES + 255) / 256)    // 1250
#define CMAP_BLOCKS ((NCHUNK + 1 + 255) / 256) // 32

typedef __attribute__((ext_vector_type(8))) short bf16x8;   // 8 bf16 = 4 VGPRs
typedef __attribute__((ext_vector_type(4))) float f32x4;
typedef __attribute__((ext_vector_type(4))) unsigned int u32x4;
typedef __attribute__((ext_vector_type(2))) unsigned int u32x2;
typedef _Float16 h2 __attribute__((ext_vector_type(2)));    // packed f16 pair (1 VGPR)

__device__ __forceinline__ unsigned short f2bf(float f) {
    unsigned u = __builtin_bit_cast(unsigned, f);
    u += 0x7FFFu + ((u >> 16) & 1u);          // round-to-nearest-even
    return (unsigned short)(u >> 16);
}
__device__ __forceinline__ float bf2f(unsigned short u) {
    return __builtin_bit_cast(float, (unsigned)u << 16);
}
__device__ __forceinline__ unsigned short f2h(float f) {
    const _Float16 h = (_Float16)f;
    return __builtin_bit_cast(unsigned short, h);
}

#if __has_builtin(__builtin_amdgcn_fdot2)
#define DOT2(a, b, c) __builtin_amdgcn_fdot2((a), (b), (c), false)
#else
__device__ __forceinline__ float dot2_fallback(h2 a, h2 b, float c) {
    return fmaf((float)a.x, (float)b.x, fmaf((float)a.y, (float)b.y, c));
}
#define DOT2(a, b, c) dot2_fallback((a), (b), (c))
#endif

// ---------------------------------------------------------------------------
// Batched converts + zero jobs: 12 jobs, one launch.
// mode 0: fp32 -> bf16 row-major     mode 1: fp32 -> f16
// mode 2: zero fill                  mode 3: fp32 W[256][K] -> MFMA-fragment
// ---------------------------------------------------------------------------
struct CvtJob  { const float* s; unsigned short* d; int n4; int mode; int kdim; };
struct CvtJobs { CvtJob j[12]; };

__global__ __launch_bounds__(256) void cvt_all(CvtJobs jobs)
{
    const CvtJob J = jobs.j[blockIdx.y];
    if (J.mode == 2) {
        const ushort4 z = {0, 0, 0, 0};
        for (int i = blockIdx.x * 256 + threadIdx.x; i < J.n4; i += gridDim.x * 256)
            ((ushort4*)J.d)[i] = z;
        return;
    }
    if (J.mode == 1) {
        for (int i = blockIdx.x * 256 + threadIdx.x; i < J.n4; i += gridDim.x * 256) {
            const float4 v = ((const float4*)J.s)[i];
            ushort4 r;
            r.x = f2h(v.x); r.y = f2h(v.y); r.z = f2h(v.z); r.w = f2h(v.w);
            ((ushort4*)J.d)[i] = r;
        }
        return;
    }
    if (J.mode == 3) {
        const int K = J.kdim, KC = K / 32;
        for (int t = blockIdx.x * 256 + threadIdx.x; t < J.n4; t += gridDim.x * 256) {
            int unit = t;
            const int lane = unit & 63; unit >>= 6;
            const int half = unit & 1;  unit >>= 1;
            const int c = unit % KC;
            const int g = unit / KC;
            const int row = g * 32 + half * 16 + (lane & 15);
            const int kb  = c * 32 + ((lane >> 4) << 3);
            const float4 v0 = *(const float4*)(J.s + (size_t)row * K + kb);
            const float4 v1 = *(const float4*)(J.s + (size_t)row * K + kb + 4);
            ushort4 r0, r1;
            r0.x = f2bf(v0.x); r0.y = f2bf(v0.y); r0.z = f2bf(v0.z); r0.w = f2bf(v0.w);
            r1.x = f2bf(v1.x); r1.y = f2bf(v1.y); r1.z = f2bf(v1.z); r1.w = f2bf(v1.w);
            ushort4* dst = (ushort4*)(J.d + (size_t)t * 8);
            dst[0] = r0; dst[1] = r1;
        }
        return;
    }
    for (int i = blockIdx.x * 256 + threadIdx.x; i < J.n4; i += gridDim.x * 256) {
        const float4 v = ((const float4*)J.s)[i];
        ushort4 r;
        r.x = f2bf(v.x); r.y = f2bf(v.y); r.z = f2bf(v.z); r.w = f2bf(v.w);
        ((ushort4*)J.d)[i] = r;
    }
}

// ---------------------------------------------------------------------------
// CSR build
// ---------------------------------------------------------------------------
__global__ __launch_bounds__(256) void hist_kernel(const int* __restrict__ dst,
                                                   int* __restrict__ deg)
{
    const int i = blockIdx.x * 256 + threadIdx.x;
    if (i < N_EDGES) atomicAdd(deg + dst[i], 1);
}

// shfl scan; writes off and cursor; tail threads also compute graph starts.
__global__ __launch_bounds__(1024) void scan_kernel(const int* __restrict__ deg,
                                                    int* __restrict__ off,
                                                    int* __restrict__ cur,
                                                    const int* __restrict__ batch,
                                                    int* __restrict__ start)
{
    __shared__ int wsum[16];
    __shared__ int carry;
    const int tid = threadIdx.x, wave = tid >> 6, lane = tid & 63;
    if (tid == 0) carry = 0;
    __syncthreads();
    for (int base = 0; base < N_NODES; base += 1024) {
        const int i = base + tid;
        const int v = (i < N_NODES) ? deg[i] : 0;
        int s = v;
#pragma unroll
        for (int d = 1; d < 64; d <<= 1) {
            const int t = __shfl_up(s, d);
            if (lane >= d) s += t;
        }
        if (lane == 63) wsum[wave] = s;
        __syncthreads();
        if (wave == 0) {
            int t = (lane < 16) ? wsum[lane] : 0;
#pragma unroll
            for (int d = 1; d < 16; d <<= 1) {
                const int u = __shfl_up(t, d);
                if (lane >= d) t += u;
            }
            if (lane < 16) wsum[lane] = t;
        }
        __syncthreads();
        const int wbase = (wave == 0) ? 0 : wsum[wave - 1];
        if (i < N_NODES) {
            const int o = carry + wbase + s - v;
            off[i] = o;
            cur[i] = o;
        }
        const int tot = wsum[15];
        __syncthreads();
        if (tid == 0) carry += tot;
        __syncthreads();
    }
    if (tid == 0) off[N_NODES] = carry;

    // graph boundaries (batch is sorted)
    if (tid <= N_GRAPHS) {
        if (tid == N_GRAPHS) { start[N_GRAPHS] = N_NODES; }
        else {
            int lo = 0, hi = N_NODES;
            while (lo < hi) { const int mid = (lo + hi) >> 1; if (batch[mid] < tid) lo = mid + 1; else hi = mid; }
            start[tid] = lo;
        }
    }
}

// scatter v3: edge blocks build CSR-sorted (src, ea_f16); trailing 32 blocks
// compute the chunk->node map (kept block-parallel — R9 lesson).
__global__ __launch_bounds__(256) void scatter_kernel(
    const int* __restrict__ src, const int* __restrict__ dst,
    const float* __restrict__ ea, int* __restrict__ cursor,
    int* __restrict__ ssrc, unsigned short* __restrict__ eas,
    const int* __restrict__ off, int* __restrict__ cmap)
{
    if (blockIdx.x >= EDGE_BLOCKS) {         // chunkmap part
        const int w = (blockIdx.x - EDGE_BLOCKS) * 256 + threadIdx.x;
        if (w > NCHUNK) return;
        if (w == NCHUNK) { cmap[w] = N_NODES; return; }
        const int target = w * CHUNK;
        int lo = 0, hi = N_NODES;            // first n with off[n] >= target
        while (lo < hi) { const int mid = (lo + hi) >> 1; if (off[mid] < target) lo = mid + 1; else hi = mid; }
        cmap[w] = lo;
        return;
    }
    const int e = blockIdx.x * 256 + threadIdx.x;
    if (e < N_EDGES) {
        const int p = atomicAdd(cursor + dst[e], 1);
        ssrc[p] = src[e];
        const float4* er = (const float4*)(ea + (size_t)e * 16);
        ushort4* d4 = (ushort4*)(eas + (size_t)p * 16);
#pragma unroll
        for (int q = 0; q < 4; ++q) {
            const float4 v = er[q];
            ushort4 r;
            r.x = f2h(v.x); r.y = f2h(v.y); r.z = f2h(v.z); r.w = f2h(v.w);
            d4[q] = r;
        }
    }
}

// ---------------------------------------------------------------------------
// agg3 v7r — REVERT of R14's column split (regressed 67->85 us: the eas/src
// loads don't split across column-waves, they duplicate; per-wave serial
// load chain unchanged). Back to the measured-best v7 structure (R13, 438us
// total). One zero-risk probe: launch_bounds(256, 8) — at VGPR=44 the
// 8-waves/EU target (<=64 VGPR) is already met, so codegen is unchanged but
// the residency floor doubles.
// out[v] = bf16( x[v] + sum_e relu(x[src] + ea@We.T + be) )
// ---------------------------------------------------------------------------
template<int IN>
__global__ __launch_bounds__(256, 8) void agg3(
    const unsigned short* __restrict__ xb,   // [M_PAD, IN] bf16
    const unsigned short* __restrict__ eas,  // [E+16,16] f16, CSR order
    const int* __restrict__ ssrc,            // [E+16] src, CSR order
    const int* __restrict__ off,             // [N+1]
    const int* __restrict__ cmap,            // [NCHUNK+1]
    const unsigned short* __restrict__ Weh,  // [IN,16] f16
    const float* __restrict__ be,
    unsigned short* __restrict__ out)        // [M_PAD, IN] bf16
{
    constexpr int CPL = IN / 64;             // 2 (layer1) or 4
    constexpr int XW  = CPL / 2;             // x-row dwords per lane: 1 or 2
    const int lane = threadIdx.x & 63;
    const int wid  = blockIdx.x * 4 + (threadIdx.x >> 6);
    const int c0 = lane * CPL;
    const int zd = __builtin_amdgcn_mbcnt_lo(0u, 0u);   // divergent zero: defeats SMEM scalarization

    // weights: CPL rows x 16 f16 — loaded once, best-effort pinned
    u32x4 wlo[CPL], whi[CPL];
    float bias[CPL], acc[CPL];
#pragma unroll
    for (int j = 0; j < CPL; ++j) {
        const u32x4* wr = (const u32x4*)(Weh + (size_t)(c0 + j) * 16);
        wlo[j] = wr[0];
        whi[j] = wr[1];
        bias[j] = be[c0 + j];
        acc[j]  = 0.0f;
    }
#pragma unroll
    for (int j = 0; j < CPL; ++j) {
#pragma unroll
        for (int k = 0; k < 4; ++k) {
            { float t = __builtin_bit_cast(float, wlo[j][k]); asm volatile("" : "+v"(t)); wlo[j][k] = __builtin_bit_cast(unsigned int, t); }
            { float t = __builtin_bit_cast(float, whi[j][k]); asm volatile("" : "+v"(t)); whi[j][k] = __builtin_bit_cast(unsigned int, t); }
        }
        asm volatile("" : "+v"(bias[j]));
    }

    int n          = __builtin_amdgcn_readfirstlane(cmap[wid]);
    const int nend = __builtin_amdgcn_readfirstlane(cmap[wid + 1]);
    if (n >= nend) return;                    // giant node spans this chunk
    int p          = __builtin_amdgcn_readfirstlane(off[n]);
    const int pend = __builtin_amdgcn_readfirstlane(off[nend]);

    auto ldx = [&](int s) -> u32x2 {          // row of xb (src gather or self)
        if constexpr (XW == 2) {
            return *(const u32x2*)(xb + (size_t)s * IN + c0);
        } else {
            u32x2 r;
            r[0] = *(const unsigned int*)(xb + (size_t)s * IN + c0);
            r[1] = 0u;
            return r;
        }
    };
    auto flushv = [&](int nn, u32x2 xs) {     // store bf16(x[nn] + acc); acc = 0
        if constexpr (XW == 2) {
            const float x0 = __builtin_bit_cast(float, xs[0] << 16);
            const float x1 = __builtin_bit_cast(float, xs[0] & 0xFFFF0000u);
            const float x2 = __builtin_bit_cast(float, xs[1] << 16);
            const float x3 = __builtin_bit_cast(float, xs[1] & 0xFFFF0000u);
            u32x2 o;
            o[0] = (unsigned)f2bf(x0 + acc[0]) | ((unsigned)f2bf(x1 + acc[1]) << 16);
            o[1] = (unsigned)f2bf(x2 + acc[2]) | ((unsigned)f2bf(x3 + acc[3]) << 16);
            *(u32x2*)(out + (size_t)nn * IN + c0) = o;
        } else {
            const float x0 = __builtin_bit_cast(float, xs[0] << 16);
            const float x1 = __builtin_bit_cast(float, xs[0] & 0xFFFF0000u);
            const unsigned int o =
                (unsigned)f2bf(x0 + acc[0]) | ((unsigned)f2bf(x1 + acc[1]) << 16);
            *(unsigned int*)(out + (size_t)nn * IN + c0) = o;
        }
#pragma unroll
        for (int j = 0; j < CPL; ++j) acc[j] = 0.0f;
    };

    // zero-degree nodes at the head of the range (immediate x loads — rare)
    int p1 = __builtin_amdgcn_readfirstlane(off[n + 1]);
    while (p1 == p) {
        flushv(n, ldx(n)); ++n;
        if (n >= nend) return;
        p1 = __builtin_amdgcn_readfirstlane(off[n + 1]);
    }
    // here: current node n non-empty, p = off[n] < p1 <= pend
    u32x2 xself = ldx(n);                     // prefetched; consumed at flush

    auto ldeL = [&](int q) -> u32x4 {        // pad reads OK: in-allocation, unused
        return ((const u32x4*)(eas + (size_t)(q + zd) * 16))[0];
    };
    auto ldeH = [&](int q) -> u32x4 {
        return ((const u32x4*)(eas + (size_t)(q + zd) * 16))[1];
    };
    auto ldsrc = [&](int q) -> int {         // CLAMPED: result is dereferenced
        const int qc = (q < N_EDGES) ? q : (N_EDGES - 1);
        return ssrc[qc + zd];
    };
    auto edge_compute = [&](u32x4 eL, u32x4 eH, u32x2 xw) {
        float m[CPL];
#pragma unroll
        for (int j = 0; j < CPL; ++j) m[j] = bias[j];
#pragma unroll
        for (int k = 0; k < 4; ++k) {
            const h2 ep = __builtin_bit_cast(h2, eL[k]);
#pragma unroll
            for (int j = 0; j < CPL; ++j)
                m[j] = DOT2(ep, __builtin_bit_cast(h2, wlo[j][k]), m[j]);
        }
#pragma unroll
        for (int k = 0; k < 4; ++k) {
            const h2 ep = __builtin_bit_cast(h2, eH[k]);
#pragma unroll
            for (int j = 0; j < CPL; ++j)
                m[j] = DOT2(ep, __builtin_bit_cast(h2, whi[j][k]), m[j]);
        }
#pragma unroll
        for (int j = 0; j < CPL; ++j) {
            const unsigned int word = xw[j >> 1];
            const float xf = __builtin_bit_cast(float,
                (j & 1) ? (word & 0xFFFF0000u) : (word << 16));
            acc[j] += fmaxf(m[j] + xf, 0.0f);
        }
    };
    // flush current node (prefetched xself) + zero-degree ties; prefetch next
    auto adv = [&]() {
        flushv(n, xself); ++n;
        while (n < nend) {
            p1 = __builtin_amdgcn_readfirstlane(off[n + 1]);
            if (p1 != p) { xself = ldx(n); break; }
            flushv(n, ldx(n)); ++n;           // zero-degree tie: immediate (rare)
        }
    };

    // depth-4 pipeline, in-place buffers, runs across node boundaries
    int sA = ldsrc(p),     sB = ldsrc(p + 1), sC = ldsrc(p + 2), sD = ldsrc(p + 3);
    u32x4 eLA = ldeL(p),     eHA = ldeH(p);
    u32x4 eLB = ldeL(p + 1), eHB = ldeH(p + 1);
    u32x4 eLC = ldeL(p + 2), eHC = ldeH(p + 2);
    u32x4 eLD = ldeL(p + 3), eHD = ldeH(p + 3);
    u32x2 xA = ldx(sA), xB = ldx(sB), xC = ldx(sC), xD = ldx(sD);
    sA = ldsrc(p + 4); sB = ldsrc(p + 5); sC = ldsrc(p + 6); sD = ldsrc(p + 7);

    for (;;) {
        edge_compute(eLA, eHA, xA);
        eLA = ldeL(p + 4); eHA = ldeH(p + 4); xA = ldx(sA); sA = ldsrc(p + 8);
        ++p; if (p == p1) adv();
        if (p >= pend) break;

        edge_compute(eLB, eHB, xB);
        eLB = ldeL(p + 4); eHB = ldeH(p + 4); xB = ldx(sB); sB = ldsrc(p + 8);
        ++p; if (p == p1) adv();
        if (p >= pend) break;

        edge_compute(eLC, eHC, xC);
        eLC = ldeL(p + 4); eHC = ldeH(p + 4); xC = ldx(sC); sC = ldsrc(p + 8);
        ++p; if (p == p1) adv();
        if (p >= pend) break;

        edge_compute(eLD, eHD, xD);
        eLD = ldeL(p + 4); eHD = ldeH(p + 4); xD = ldx(sD); sD = ldsrc(p + 8);
        ++p; if (p == p1) adv();
        if (p >= pend) break;
    }
    // safety: trailing zero-degree nodes (normally handled by adv)
    while (n < nend) { flushv(n, ldx(n)); ++n; }
}

// ---------------------------------------------------------------------------
// gemm_fused v3 (kept from R12, −17 us: frag-packed B). Both GEMMs of a GINE
// layer in one 512-thread kernel: LDS A-tile (XOR 16B-slot swizzle), stage1
// MFMA (Wa frags coalesced) -> BN+relu -> swizzled t tile in LDS, barrier,
// stage2 MFMA (Wb frags) -> bias+relu -> h.
// ---------------------------------------------------------------------------
template<int K>
__global__ __launch_bounds__(512, 4) void gemm_fused(
    const unsigned short* __restrict__ A,    // [M_PAD, K] (u)
    const unsigned short* __restrict__ WaF,  // frag-packed Wa (g,c,half,lane)
    const float* __restrict__ ba,
    const float* __restrict__ gsc, const float* __restrict__ bsh,
    const unsigned short* __restrict__ WbF,  // frag-packed Wb
    const float* __restrict__ bb,
    unsigned short* __restrict__ out)        // [M_PAD, 256] (h)
{
    constexpr int KC1 = K / 32;              // stage1 k-chunks: 4 or 8
    constexpr int KC2 = H / 32;              // stage2 k-chunks: 8
    constexpr int SLOTS = K / 8;             // 16B slots per A row
    __shared__ unsigned short Al[64 * K];    // 16/32 KB
    __shared__ unsigned short Tl[64 * H];    // 32 KB, swizzled slots

    const int w = threadIdx.x >> 6, lane = threadIdx.x & 63;
    const int lm = lane & 15, lq = lane >> 4;
    const int n0 = w * 32;                   // this wave's 32 output cols
    const int m0 = blockIdx.x * 64;

    const bf16x8* Wa8 = (const bf16x8*)WaF;
    const bf16x8* Wb8 = (const bf16x8*)WbF;

    // cooperative A-tile stage (512 threads), XOR-swizzled 16B slots
#pragma unroll
    for (int i = 0; i < 64 * SLOTS / 512; ++i) {
        const int t = i * 512 + threadIdx.x;
        const int row = t / SLOTS, slot = t % SLOTS;
        const uint4 v = *(const uint4*)(A + (size_t)(m0 + row) * K + slot * 8);
        *(uint4*)((char*)Al + row * (K * 2) + ((slot ^ (row & 7)) * 16)) = v;
    }

    const float inv = rsqrtf(1.0f + 1e-5f);
    const float bc0 = ba[n0 + lm],  bc1 = ba[n0 + 16 + lm];
    const float gc0 = gsc[n0 + lm], gc1 = gsc[n0 + 16 + lm];
    const float sc0 = bsh[n0 + lm], sc1 = bsh[n0 + 16 + lm];

    __syncthreads();

    // ---- stage 1: t = relu((u@Wa^T + ba)*inv*g + bt) -> LDS (half-K passes)
    {
        f32x4 acc0[4], acc1[4];
#pragma unroll
        for (int ch = 0; ch < 4; ++ch) {
            acc0[ch] = (f32x4){0.f, 0.f, 0.f, 0.f};
            acc1[ch] = (f32x4){0.f, 0.f, 0.f, 0.f};
        }
#pragma unroll
        for (int kh = 0; kh < KC1; kh += 4) {
            bf16x8 C0[4], C1[4];
#pragma unroll
            for (int c = 0; c < 4; ++c) {
                const int fi = (w * KC1 + kh + c) * 2;
                C0[c] = Wa8[(size_t)(fi + 0) * 64 + lane];
                C1[c] = Wa8[(size_t)(fi + 1) * 64 + lane];
            }
#pragma unroll
            for (int ch = 0; ch < 4; ++ch) {
                const int row = ch * 16 + lm;
                const char* rbase = (const char*)Al + row * (K * 2);
#pragma unroll
                for (int c = 0; c < 4; ++c) {
                    const int slot = (lq + (kh + c) * 4) ^ (row & 7);
                    const bf16x8 a = *(const bf16x8*)(rbase + slot * 16);
                    acc0[ch] = __builtin_amdgcn_mfma_f32_16x16x32_bf16(a, C0[c], acc0[ch], 0, 0, 0);
                    acc1[ch] = __builtin_amdgcn_mfma_f32_16x16x32_bf16(a, C1[c], acc1[ch], 0, 0, 0);
                }
            }
        }
        // write t tile to LDS (bf16, swizzled slots)
#pragma unroll
        for (int ch = 0; ch < 4; ++ch) {
#pragma unroll
            for (int r = 0; r < 4; ++r) {
                const int rowo = ch * 16 + lq * 4 + r;
                const float v0 = fmaxf((acc0[ch][r] + bc0) * inv * gc0 + sc0, 0.0f);
                const float v1 = fmaxf((acc1[ch][r] + bc1) * inv * gc1 + sc1, 0.0f);
                const int col0 = n0 + lm, col1 = n0 + 16 + lm;
                *(unsigned short*)((char*)Tl + rowo * (H * 2)
                    + (((col0 >> 3) ^ (rowo & 7)) << 4) + ((col0 & 7) << 1)) = f2bf(v0);
                *(unsigned short*)((char*)Tl + rowo * (H * 2)
                    + (((col1 >> 3) ^ (rowo & 7)) << 4) + ((col1 & 7) << 1)) = f2bf(v1);
            }
        }
    }

    const float eb0 = bb[n0 + lm], eb1 = bb[n0 + 16 + lm];

    __syncthreads();

    // ---- stage 2: h = relu(t @ Wb^T + bb) (half-K passes)
    {
        f32x4 acc0[4], acc1[4];
#pragma unroll
        for (int ch = 0; ch < 4; ++ch) {
            acc0[ch] = (f32x4){0.f, 0.f, 0.f, 0.f};
            acc1[ch] = (f32x4){0.f, 0.f, 0.f, 0.f};
        }
#pragma unroll
        for (int kh = 0; kh < KC2; kh += 4) {
            bf16x8 C0[4], C1[4];
#pragma unroll
            for (int c = 0; c < 4; ++c) {
                const int fi = (w * KC2 + kh + c) * 2;
                C0[c] = Wb8[(size_t)(fi + 0) * 64 + lane];
                C1[c] = Wb8[(size_t)(fi + 1) * 64 + lane];
            }
#pragma unroll
            for (int ch = 0; ch < 4; ++ch) {
                const int row = ch * 16 + lm;
                const char* rbase = (const char*)Tl + row * (H * 2);
#pragma unroll
                for (int c = 0; c < 4; ++c) {
                    const int slot = (lq + (kh + c) * 4) ^ (row & 7);
                    const bf16x8 a = *(const bf16x8*)(rbase + slot * 16);
                    acc0[ch] = __builtin_amdgcn_mfma_f32_16x16x32_bf16(a, C0[c], acc0[ch], 0, 0, 0);
                    acc1[ch] = __builtin_amdgcn_mfma_f32_16x16x32_bf16(a, C1[c], acc1[ch], 0, 0, 0);
                }
            }
        }
#pragma unroll
        for (int ch = 0; ch < 4; ++ch) {
            const int mr = m0 + ch * 16;
#pragma unroll
            for (int r = 0; r < 4; ++r) {
                const int rowo = mr + lq * 4 + r;
                if (rowo >= N_NODES) continue;
                const float v0 = fmaxf(acc0[ch][r] + eb0, 0.0f);
                const float v1 = fmaxf(acc1[ch][r] + eb1, 0.0f);
                out[(size_t)rowo * H + n0 + lm]      = f2bf(v0);
                out[(size_t)rowo * H + n0 + 16 + lm] = f2bf(v1);
            }
        }
    }
}

// ---------------------------------------------------------------------------
// pool2 v2 (R13 win): u32x4 vectorized loads, 8 rows in flight, LDS
// cross-rowgroup reduce, one atomic per column.
// ---------------------------------------------------------------------------
#define RSPLIT 6
__global__ __launch_bounds__(256) void pool2(
    const unsigned short* __restrict__ h1, const unsigned short* __restrict__ h2,
    const unsigned short* __restrict__ h3, const int* __restrict__ start,
    float* __restrict__ pool)
{
    const int g = blockIdx.x & 63, layer = blockIdx.x >> 6;
    const unsigned short* h = (layer == 0) ? h1 : (layer == 1) ? h2 : h3;
    const int r0 = start[g], r1 = start[g + 1];
    const int nr = r1 - r0;
    if (nr <= 0) return;
    const int chunk = (nr + RSPLIT - 1) / RSPLIT;
    const int rs = r0 + blockIdx.y * chunk;
    const int re = (rs + chunk < r1) ? rs + chunk : r1;
    if (rs >= re) return;

    const int cg = threadIdx.x & 31;         // cols cg*8 .. cg*8+7
    const int rg = threadIdx.x >> 5;         // row group 0..7
    float s0 = 0.f, s1 = 0.f, s2 = 0.f, s3 = 0.f;
    float s4 = 0.f, s5 = 0.f, s6 = 0.f, s7 = 0.f;
    for (int r = rs + rg; r < re; r += 8) {
        const u32x4 v = *(const u32x4*)(h + (size_t)r * H + cg * 8);
        s0 += __builtin_bit_cast(float, v[0] << 16);
        s1 += __builtin_bit_cast(float, v[0] & 0xFFFF0000u);
        s2 += __builtin_bit_cast(float, v[1] << 16);
        s3 += __builtin_bit_cast(float, v[1] & 0xFFFF0000u);
        s4 += __builtin_bit_cast(float, v[2] << 16);
        s5 += __builtin_bit_cast(float, v[2] & 0xFFFF0000u);
        s6 += __builtin_bit_cast(float, v[3] << 16);
        s7 += __builtin_bit_cast(float, v[3] & 0xFFFF0000u);
    }
    __shared__ float red[8][256];
    red[rg][cg * 8 + 0] = s0; red[rg][cg * 8 + 1] = s1;
    red[rg][cg * 8 + 2] = s2; red[rg][cg * 8 + 3] = s3;
    red[rg][cg * 8 + 4] = s4; red[rg][cg * 8 + 5] = s5;
    red[rg][cg * 8 + 6] = s6; red[rg][cg * 8 + 7] = s7;
    __syncthreads();
    float t = 0.f;
#pragma unroll
    for (int q = 0; q < 8; ++q) t += red[q][threadIdx.x];
    atomicAdd(&pool[(size_t)g * POOL_W + layer * 256 + threadIdx.x], t);
}

// ---------------------------------------------------------------------------
// fc_head v3 (R13 win): two graphs per block — each L1w fragment loaded once
// and dotted against both p-vectors. Grid (32, 12).
// ---------------------------------------------------------------------------
__global__ __launch_bounds__(256) void fc_head(
    const float* __restrict__ pool, const int* __restrict__ start,
    const float* __restrict__ L1w, const float* __restrict__ L1b,
    const float* __restrict__ L2w, float* __restrict__ gsum)
{
    const int g0 = blockIdx.x * 2, g1 = g0 + 1;
    __shared__ float p[2][POOL_W];

    const float rc0 = 1.0f / fmaxf((float)(start[g0 + 1] - start[g0]), 1.0f);
    const float rc1 = 1.0f / fmaxf((float)(start[g1 + 1] - start[g1]), 1.0f);
    for (int i = threadIdx.x; i < POOL_W; i += 256) {
        p[0][i] = pool[(size_t)g0 * POOL_W + i] * rc0;
        p[1][i] = pool[(size_t)g1 * POOL_W + i] * rc1;
    }
    __syncthreads();

    const int wv = threadIdx.x >> 6, lane = threadIdx.x & 63;
    const float4* pA = (const float4*)p[0];
    const float4* pB = (const float4*)p[1];
    const float4 a0 = pA[lane], a1 = pA[lane + 64], a2 = pA[lane + 128];
    const float4 b0 = pB[lane], b1 = pB[lane + 64], b2 = pB[lane + 128];

    const int ob = blockIdx.y * 64 + wv * 16;
    float part0 = 0.0f, part1 = 0.0f;
#pragma unroll 4
    for (int t = 0; t < 16; ++t) {
        const int o = ob + t;
        const float4* wr = (const float4*)(L1w + (size_t)o * POOL_W);
        const float4 wa = wr[lane], wb = wr[lane + 64], wc = wr[lane + 128];
        float accA = wa.x * a0.x + wa.y * a0.y + wa.z * a0.z + wa.w * a0.w
                   + wb.x * a1.x + wb.y * a1.y + wb.z * a1.z + wb.w * a1.w
                   + wc.x * a2.x + wc.y * a2.y + wc.z * a2.z + wc.w * a2.w;
        float accB = wa.x * b0.x + wa.y * b0.y + wa.z * b0.z + wa.w * b0.w
                   + wb.x * b1.x + wb.y * b1.y + wb.z * b1.z + wb.w * b1.w
                   + wc.x * b2.x + wc.y * b2.y + wc.z * b2.z + wc.w * b2.w;
#pragma unroll
        for (int off = 32; off > 0; off >>= 1) {
            accA += __shfl_xor(accA, off);
            accB += __shfl_xor(accB, off);
        }
        if (lane == 0) {
            const float r = fmaxf(accA + L1b[o], 0.0f);
            const float s = fmaxf(accB + L1b[o], 0.0f);
            part0 += r * L2w[o];
            part1 += s * L2w[o];
        }
    }
    if (lane == 0) {
        atomicAdd(&gsum[g0], part0);
        atomicAdd(&gsum[g1], part1);
    }
}

__global__ __launch_bounds__(64) void sig_kernel(
    const float* __restrict__ gsum, const float* __restrict__ L2b,
    float* __restrict__ out)
{
    const int g = threadIdx.x;
    if (g < N_GRAPHS) out[g] = 1.0f / (1.0f + expf(-(gsum[g] + L2b[0])));
}

// ---------------------------------------------------------------------------
extern "C" void kernel_launch(void* const* d_in, const int* in_sizes, int n_in,
                              void* d_out, int out_size, void* d_ws, size_t ws_size,
                              hipStream_t stream)
{
    const float* x     = (const float*)d_in[0];
    const float* ea    = (const float*)d_in[1];
    const int*   src   = (const int*)d_in[2];
    const int*   dst   = (const int*)d_in[3];
    const int*   batch = (const int*)d_in[4];

    const float* We[3]; const float* be[3]; const float* Wa[3]; const float* ba[3];
    const float* gg[3]; const float* bt[3]; const float* Wb[3]; const float* bb[3];
    for (int l = 0; l < 3; ++l) {
        const int o = 5 + 8 * l;
        We[l] = (const float*)d_in[o + 0]; be[l] = (const float*)d_in[o + 1];
        Wa[l] = (const float*)d_in[o + 2]; ba[l] = (const float*)d_in[o + 3];
        gg[l] = (const float*)d_in[o + 4]; bt[l] = (const float*)d_in[o + 5];
        Wb[l] = (const float*)d_in[o + 6]; bb[l] = (const float*)d_in[o + 7];
    }
    const float* L1w = (const float*)d_in[29];
    const float* L1b = (const float*)d_in[30];
    const float* L2w = (const float*)d_in[31];
    const float* L2b = (const float*)d_in[32];

    // ---- workspace layout ----
    float* pool   = (float*)d_ws;                              // 64*768
    float* gsum   = pool + (size_t)N_GRAPHS * POOL_W;          // 64 (zeroed with pool)
    int*   deg    = (int*)(gsum + N_GRAPHS);                   // N
    int*   off    = deg + N_NODES;                             // N+1
    int*   cursor = off + N_NODES + 1;                         // N
    int*   start  = cursor + N_NODES;                          // 72
    int*   cmap   = start + 72;                                // NCHUNK+1
    int*   ssrc   = (int*)((((uintptr_t)(cmap + NCHUNK + 1)) + 31) & ~(uintptr_t)31);  // E+16 ints, CSR
    unsigned short* eas = (unsigned short*)((((uintptr_t)(ssrc + N_EDGES + 16)) + 31) & ~(uintptr_t)31); // [E+16,16] f16 CSR
    unsigned short* xb = (unsigned short*)((((uintptr_t)(eas + (size_t)(N_EDGES + 16) * 16)) + 31) & ~(uintptr_t)31);
    unsigned short* u  = xb + (size_t)M_PAD * DIN;             // [M_PAD,256] (layer1 uses 128)
    unsigned short* h1 = u  + (size_t)M_PAD * H;
    unsigned short* h2 = h1 + (size_t)M_PAD * H;
    unsigned short* h3 = h2 + (size_t)M_PAD * H;
    unsigned short* wbf[6];
    wbf[0] = h3 + (size_t)M_PAD * H;                           // Wa1 frag [256,128]
    wbf[1] = wbf[0] + H * DIN;
    for (int i = 2; i < 6; ++i) wbf[i] = wbf[i - 1] + H * H;
    unsigned short* weh[3];
    weh[0] = wbf[5] + H * H;                                   // We1 [128,16] f16
    weh[1] = weh[0] + DIN * 16;                                // We2 [256,16] f16
    weh[2] = weh[1] + H * 16;                                  // We3 [256,16] f16

    // batched converts + deg/pool+gsum zeroing in one launch (12 jobs)
    CvtJobs jobs;
    jobs.j[0]  = { x,       xb,                    N_NODES * DIN / 4,       0, 0 };
    jobs.j[1]  = { Wa[0],   wbf[0],                H * DIN / 8,             3, DIN };
    jobs.j[2]  = { Wb[0],   wbf[1],                H * H / 8,               3, H };
    jobs.j[3]  = { Wa[1],   wbf[2],                H * H / 8,               3, H };
    jobs.j[4]  = { Wb[1],   wbf[3],                H * H / 8,               3, H };
    jobs.j[5]  = { Wa[2],   wbf[4],                H * H / 8,               3, H };
    jobs.j[6]  = { Wb[2],   wbf[5],                H * H / 8,               3, H };
    jobs.j[7]  = { nullptr, (unsigned short*)deg,  N_NODES * 4 / 8,         2, 0 };  // zero N ints
    jobs.j[8]  = { nullptr, (unsigned short*)pool, (N_GRAPHS * POOL_W + N_GRAPHS) * 4 / 8, 2, 0 }; // zero pool+gsum
    jobs.j[9]  = { We[0],   weh[0],                DIN * 16 / 4,            1, 0 };
    jobs.j[10] = { We[1],   weh[1],                H * 16 / 4,              1, 0 };
    jobs.j[11] = { We[2],   weh[2],                H * 16 / 4,              1, 0 };
    cvt_all<<<dim3(320, 12), 256, 0, stream>>>(jobs);

    // CSR + graph boundaries; scatter also computes the chunk map (merged)
    hist_kernel<<<EDGE_BLOCKS, 256, 0, stream>>>(dst, deg);
    scan_kernel<<<1, 1024, 0, stream>>>(deg, off, cursor, batch, start);
    scatter_kernel<<<EDGE_BLOCKS + CMAP_BLOCKS, 256, 0, stream>>>(
        src, dst, ea, cursor, ssrc, eas, off, cmap);

    const int agrid = NCHUNK / 4;               // agg3: 1 chunk/wave, 4 waves/block
    const int ggrid = M_PAD / 64;               // gemm_fused: 313 blocks x 512

    // ---- layer 1 (in=128) ----
    agg3<DIN><<<agrid, 256, 0, stream>>>(xb, eas, ssrc, off, cmap, weh[0], be[0], u);
    gemm_fused<DIN><<<ggrid, 512, 0, stream>>>(u, wbf[0], ba[0], gg[0], bt[0], wbf[1], bb[0], h1);
    // ---- layer 2 ----
    agg3<H><<<agrid, 256, 0, stream>>>(h1, eas, ssrc, off, cmap, weh[1], be[1], u);
    gemm_fused<H><<<ggrid, 512, 0, stream>>>(u, wbf[2], ba[1], gg[1], bt[1], wbf[3], bb[1], h2);
    // ---- layer 3 ----
    agg3<H><<<agrid, 256, 0, stream>>>(h2, eas, ssrc, off, cmap, weh[2], be[2], u);
    gemm_fused<H><<<ggrid, 512, 0, stream>>>(u, wbf[4], ba[2], gg[2], bt[2], wbf[5], bb[2], h3);

    // parallel mean-pool + head (fc_head: 2 graphs/block)
    pool2<<<dim3(3 * N_GRAPHS, RSPLIT), 256, 0, stream>>>(h1, h2, h3, start, pool);
    fc_head<<<dim3(N_GRAPHS / 2, POOL_W / 64), 256, 0, stream>>>(pool, start, L1w, L1b, L2w, gsum);
    sig_kernel<<<1, 64, 0, stream>>>(gsum, L2b, (float*)d_out);
}

// Round 16
// 443.547 us; speedup vs baseline: 1.1614x; 1.1614x over previous
//
#include <hip/hip_runtime.h>
#include <math.h>
#include <stdint.h>

#define N_NODES 20000
#define M_PAD 20032            // 313 * 64
#define N_EDGES 320000
#define N_GRAPHS 64
#define DIN 128
#define H 256
#define POOL_W 768
#define CHUNK 40               // edges per wave in agg3
#define NCHUNK (N_EDGES / CHUNK)   // 8000 (exact)
#define EDGE_BLOCKS ((N_EDGES + 255) / 256)    // 1250
#define CMAP_BLOCKS ((NCHUNK + 1 + 255) / 256) // 32

typedef __attribute__((ext_vector_type(8))) short bf16x8;   // 8 bf16 = 4 VGPRs
typedef __attribute__((ext_vector_type(4))) float f32x4;
typedef __attribute__((ext_vector_type(4))) unsigned int u32x4;
typedef __attribute__((ext_vector_type(2))) unsigned int u32x2;
typedef _Float16 h2 __attribute__((ext_vector_type(2)));    // packed f16 pair (1 VGPR)

__device__ __forceinline__ unsigned short f2bf(float f) {
    unsigned u = __builtin_bit_cast(unsigned, f);
    u += 0x7FFFu + ((u >> 16) & 1u);          // round-to-nearest-even
    return (unsigned short)(u >> 16);
}
__device__ __forceinline__ float bf2f(unsigned short u) {
    return __builtin_bit_cast(float, (unsigned)u << 16);
}
__device__ __forceinline__ unsigned short f2h(float f) {
    const _Float16 h = (_Float16)f;
    return __builtin_bit_cast(unsigned short, h);
}

#if __has_builtin(__builtin_amdgcn_fdot2)
#define DOT2(a, b, c) __builtin_amdgcn_fdot2((a), (b), (c), false)
#else
__device__ __forceinline__ float dot2_fallback(h2 a, h2 b, float c) {
    return fmaf((float)a.x, (float)b.x, fmaf((float)a.y, (float)b.y, c));
}
#define DOT2(a, b, c) dot2_fallback((a), (b), (c))
#endif

// ---------------------------------------------------------------------------
// Batched converts + zero jobs: 12 jobs, one launch.
// mode 0: fp32 -> bf16 row-major     mode 1: fp32 -> f16
// mode 2: zero fill                  mode 3: fp32 W[256][K] -> MFMA-fragment
// ---------------------------------------------------------------------------
struct CvtJob  { const float* s; unsigned short* d; int n4; int mode; int kdim; };
struct CvtJobs { CvtJob j[12]; };

__global__ __launch_bounds__(256) void cvt_all(CvtJobs jobs)
{
    const CvtJob J = jobs.j[blockIdx.y];
    if (J.mode == 2) {
        const ushort4 z = {0, 0, 0, 0};
        for (int i = blockIdx.x * 256 + threadIdx.x; i < J.n4; i += gridDim.x * 256)
            ((ushort4*)J.d)[i] = z;
        return;
    }
    if (J.mode == 1) {
        for (int i = blockIdx.x * 256 + threadIdx.x; i < J.n4; i += gridDim.x * 256) {
            const float4 v = ((const float4*)J.s)[i];
            ushort4 r;
            r.x = f2h(v.x); r.y = f2h(v.y); r.z = f2h(v.z); r.w = f2h(v.w);
            ((ushort4*)J.d)[i] = r;
        }
        return;
    }
    if (J.mode == 3) {
        const int K = J.kdim, KC = K / 32;
        for (int t = blockIdx.x * 256 + threadIdx.x; t < J.n4; t += gridDim.x * 256) {
            int unit = t;
            const int lane = unit & 63; unit >>= 6;
            const int half = unit & 1;  unit >>= 1;
            const int c = unit % KC;
            const int g = unit / KC;
            const int row = g * 32 + half * 16 + (lane & 15);
            const int kb  = c * 32 + ((lane >> 4) << 3);
            const float4 v0 = *(const float4*)(J.s + (size_t)row * K + kb);
            const float4 v1 = *(const float4*)(J.s + (size_t)row * K + kb + 4);
            ushort4 r0, r1;
            r0.x = f2bf(v0.x); r0.y = f2bf(v0.y); r0.z = f2bf(v0.z); r0.w = f2bf(v0.w);
            r1.x = f2bf(v1.x); r1.y = f2bf(v1.y); r1.z = f2bf(v1.z); r1.w = f2bf(v1.w);
            ushort4* dst = (ushort4*)(J.d + (size_t)t * 8);
            dst[0] = r0; dst[1] = r1;
        }
        return;
    }
    for (int i = blockIdx.x * 256 + threadIdx.x; i < J.n4; i += gridDim.x * 256) {
        const float4 v = ((const float4*)J.s)[i];
        ushort4 r;
        r.x = f2bf(v.x); r.y = f2bf(v.y); r.z = f2bf(v.z); r.w = f2bf(v.w);
        ((ushort4*)J.d)[i] = r;
    }
}

// ---------------------------------------------------------------------------
// CSR build
// ---------------------------------------------------------------------------
__global__ __launch_bounds__(256) void hist_kernel(const int* __restrict__ dst,
                                                   int* __restrict__ deg)
{
    const int i = blockIdx.x * 256 + threadIdx.x;
    if (i < N_EDGES) atomicAdd(deg + dst[i], 1);
}

// shfl scan; writes off and cursor; tail threads also compute graph starts.
__global__ __launch_bounds__(1024) void scan_kernel(const int* __restrict__ deg,
                                                    int* __restrict__ off,
                                                    int* __restrict__ cur,
                                                    const int* __restrict__ batch,
                                                    int* __restrict__ start)
{
    __shared__ int wsum[16];
    __shared__ int carry;
    const int tid = threadIdx.x, wave = tid >> 6, lane = tid & 63;
    if (tid == 0) carry = 0;
    __syncthreads();
    for (int base = 0; base < N_NODES; base += 1024) {
        const int i = base + tid;
        const int v = (i < N_NODES) ? deg[i] : 0;
        int s = v;
#pragma unroll
        for (int d = 1; d < 64; d <<= 1) {
            const int t = __shfl_up(s, d);
            if (lane >= d) s += t;
        }
        if (lane == 63) wsum[wave] = s;
        __syncthreads();
        if (wave == 0) {
            int t = (lane < 16) ? wsum[lane] : 0;
#pragma unroll
            for (int d = 1; d < 16; d <<= 1) {
                const int u = __shfl_up(t, d);
                if (lane >= d) t += u;
            }
            if (lane < 16) wsum[lane] = t;
        }
        __syncthreads();
        const int wbase = (wave == 0) ? 0 : wsum[wave - 1];
        if (i < N_NODES) {
            const int o = carry + wbase + s - v;
            off[i] = o;
            cur[i] = o;
        }
        const int tot = wsum[15];
        __syncthreads();
        if (tid == 0) carry += tot;
        __syncthreads();
    }
    if (tid == 0) off[N_NODES] = carry;

    // graph boundaries (batch is sorted)
    if (tid <= N_GRAPHS) {
        if (tid == N_GRAPHS) { start[N_GRAPHS] = N_NODES; }
        else {
            int lo = 0, hi = N_NODES;
            while (lo < hi) { const int mid = (lo + hi) >> 1; if (batch[mid] < tid) lo = mid + 1; else hi = mid; }
            start[tid] = lo;
        }
    }
}

// scatter v3: edge blocks build CSR-sorted (src, ea_f16); trailing 32 blocks
// compute the chunk->node map (kept block-parallel — R9 lesson).
__global__ __launch_bounds__(256) void scatter_kernel(
    const int* __restrict__ src, const int* __restrict__ dst,
    const float* __restrict__ ea, int* __restrict__ cursor,
    int* __restrict__ ssrc, unsigned short* __restrict__ eas,
    const int* __restrict__ off, int* __restrict__ cmap)
{
    if (blockIdx.x >= EDGE_BLOCKS) {         // chunkmap part
        const int w = (blockIdx.x - EDGE_BLOCKS) * 256 + threadIdx.x;
        if (w > NCHUNK) return;
        if (w == NCHUNK) { cmap[w] = N_NODES; return; }
        const int target = w * CHUNK;
        int lo = 0, hi = N_NODES;            // first n with off[n] >= target
        while (lo < hi) { const int mid = (lo + hi) >> 1; if (off[mid] < target) lo = mid + 1; else hi = mid; }
        cmap[w] = lo;
        return;
    }
    const int e = blockIdx.x * 256 + threadIdx.x;
    if (e < N_EDGES) {
        const int p = atomicAdd(cursor + dst[e], 1);
        ssrc[p] = src[e];
        const float4* er = (const float4*)(ea + (size_t)e * 16);
        ushort4* d4 = (ushort4*)(eas + (size_t)p * 16);
#pragma unroll
        for (int q = 0; q < 4; ++q) {
            const float4 v = er[q];
            ushort4 r;
            r.x = f2h(v.x); r.y = f2h(v.y); r.z = f2h(v.z); r.w = f2h(v.w);
            d4[q] = r;
        }
    }
}

// ---------------------------------------------------------------------------
// agg3 v7 — EXACT R13 measured-best config (67 us, VGPR=44, total 438).
// R15 LESSON: launch_bounds(256,8) forced VGPR 44->32 and spilled the
// pipeline to scratch (WRITE_SIZE 10->154 MB, 67->105 us). min-waves is a
// REGISTER CAP, never a free hint. Keep (256,4).
// Edge-parallel segmented aggregation: 8000 waves x 40-edge CSR chunks,
// depth-4 in-place pipeline across node boundaries, wave-uniform SALU
// flush, xself prefetched at node entry.
// out[v] = bf16( x[v] + sum_e relu(x[src] + ea@We.T + be) )
// ---------------------------------------------------------------------------
template<int IN>
__global__ __launch_bounds__(256, 4) void agg3(
    const unsigned short* __restrict__ xb,   // [M_PAD, IN] bf16
    const unsigned short* __restrict__ eas,  // [E+16,16] f16, CSR order
    const int* __restrict__ ssrc,            // [E+16] src, CSR order
    const int* __restrict__ off,             // [N+1]
    const int* __restrict__ cmap,            // [NCHUNK+1]
    const unsigned short* __restrict__ Weh,  // [IN,16] f16
    const float* __restrict__ be,
    unsigned short* __restrict__ out)        // [M_PAD, IN] bf16
{
    constexpr int CPL = IN / 64;             // 2 (layer1) or 4
    constexpr int XW  = CPL / 2;             // x-row dwords per lane: 1 or 2
    const int lane = threadIdx.x & 63;
    const int wid  = blockIdx.x * 4 + (threadIdx.x >> 6);
    const int c0 = lane * CPL;
    const int zd = __builtin_amdgcn_mbcnt_lo(0u, 0u);   // divergent zero: defeats SMEM scalarization

    // weights: CPL rows x 16 f16 — loaded once, best-effort pinned
    u32x4 wlo[CPL], whi[CPL];
    float bias[CPL], acc[CPL];
#pragma unroll
    for (int j = 0; j < CPL; ++j) {
        const u32x4* wr = (const u32x4*)(Weh + (size_t)(c0 + j) * 16);
        wlo[j] = wr[0];
        whi[j] = wr[1];
        bias[j] = be[c0 + j];
        acc[j]  = 0.0f;
    }
#pragma unroll
    for (int j = 0; j < CPL; ++j) {
#pragma unroll
        for (int k = 0; k < 4; ++k) {
            { float t = __builtin_bit_cast(float, wlo[j][k]); asm volatile("" : "+v"(t)); wlo[j][k] = __builtin_bit_cast(unsigned int, t); }
            { float t = __builtin_bit_cast(float, whi[j][k]); asm volatile("" : "+v"(t)); whi[j][k] = __builtin_bit_cast(unsigned int, t); }
        }
        asm volatile("" : "+v"(bias[j]));
    }

    int n          = __builtin_amdgcn_readfirstlane(cmap[wid]);
    const int nend = __builtin_amdgcn_readfirstlane(cmap[wid + 1]);
    if (n >= nend) return;                    // giant node spans this chunk
    int p          = __builtin_amdgcn_readfirstlane(off[n]);
    const int pend = __builtin_amdgcn_readfirstlane(off[nend]);

    auto ldx = [&](int s) -> u32x2 {          // row of xb (src gather or self)
        if constexpr (XW == 2) {
            return *(const u32x2*)(xb + (size_t)s * IN + c0);
        } else {
            u32x2 r;
            r[0] = *(const unsigned int*)(xb + (size_t)s * IN + c0);
            r[1] = 0u;
            return r;
        }
    };
    auto flushv = [&](int nn, u32x2 xs) {     // store bf16(x[nn] + acc); acc = 0
        if constexpr (XW == 2) {
            const float x0 = __builtin_bit_cast(float, xs[0] << 16);
            const float x1 = __builtin_bit_cast(float, xs[0] & 0xFFFF0000u);
            const float x2 = __builtin_bit_cast(float, xs[1] << 16);
            const float x3 = __builtin_bit_cast(float, xs[1] & 0xFFFF0000u);
            u32x2 o;
            o[0] = (unsigned)f2bf(x0 + acc[0]) | ((unsigned)f2bf(x1 + acc[1]) << 16);
            o[1] = (unsigned)f2bf(x2 + acc[2]) | ((unsigned)f2bf(x3 + acc[3]) << 16);
            *(u32x2*)(out + (size_t)nn * IN + c0) = o;
        } else {
            const float x0 = __builtin_bit_cast(float, xs[0] << 16);
            const float x1 = __builtin_bit_cast(float, xs[0] & 0xFFFF0000u);
            const unsigned int o =
                (unsigned)f2bf(x0 + acc[0]) | ((unsigned)f2bf(x1 + acc[1]) << 16);
            *(unsigned int*)(out + (size_t)nn * IN + c0) = o;
        }
#pragma unroll
        for (int j = 0; j < CPL; ++j) acc[j] = 0.0f;
    };

    // zero-degree nodes at the head of the range (immediate x loads — rare)
    int p1 = __builtin_amdgcn_readfirstlane(off[n + 1]);
    while (p1 == p) {
        flushv(n, ldx(n)); ++n;
        if (n >= nend) return;
        p1 = __builtin_amdgcn_readfirstlane(off[n + 1]);
    }
    // here: current node n non-empty, p = off[n] < p1 <= pend
    u32x2 xself = ldx(n);                     // prefetched; consumed at flush

    auto ldeL = [&](int q) -> u32x4 {        // pad reads OK: in-allocation, unused
        return ((const u32x4*)(eas + (size_t)(q + zd) * 16))[0];
    };
    auto ldeH = [&](int q) -> u32x4 {
        return ((const u32x4*)(eas + (size_t)(q + zd) * 16))[1];
    };
    auto ldsrc = [&](int q) -> int {         // CLAMPED: result is dereferenced
        const int qc = (q < N_EDGES) ? q : (N_EDGES - 1);
        return ssrc[qc + zd];
    };
    auto edge_compute = [&](u32x4 eL, u32x4 eH, u32x2 xw) {
        float m[CPL];
#pragma unroll
        for (int j = 0; j < CPL; ++j) m[j] = bias[j];
#pragma unroll
        for (int k = 0; k < 4; ++k) {
            const h2 ep = __builtin_bit_cast(h2, eL[k]);
#pragma unroll
            for (int j = 0; j < CPL; ++j)
                m[j] = DOT2(ep, __builtin_bit_cast(h2, wlo[j][k]), m[j]);
        }
#pragma unroll
        for (int k = 0; k < 4; ++k) {
            const h2 ep = __builtin_bit_cast(h2, eH[k]);
#pragma unroll
            for (int j = 0; j < CPL; ++j)
                m[j] = DOT2(ep, __builtin_bit_cast(h2, whi[j][k]), m[j]);
        }
#pragma unroll
        for (int j = 0; j < CPL; ++j) {
            const unsigned int word = xw[j >> 1];
            const float xf = __builtin_bit_cast(float,
                (j & 1) ? (word & 0xFFFF0000u) : (word << 16));
            acc[j] += fmaxf(m[j] + xf, 0.0f);
        }
    };
    // flush current node (prefetched xself) + zero-degree ties; prefetch next
    auto adv = [&]() {
        flushv(n, xself); ++n;
        while (n < nend) {
            p1 = __builtin_amdgcn_readfirstlane(off[n + 1]);
            if (p1 != p) { xself = ldx(n); break; }
            flushv(n, ldx(n)); ++n;           // zero-degree tie: immediate (rare)
        }
    };

    // depth-4 pipeline, in-place buffers, runs across node boundaries
    int sA = ldsrc(p),     sB = ldsrc(p + 1), sC = ldsrc(p + 2), sD = ldsrc(p + 3);
    u32x4 eLA = ldeL(p),     eHA = ldeH(p);
    u32x4 eLB = ldeL(p + 1), eHB = ldeH(p + 1);
    u32x4 eLC = ldeL(p + 2), eHC = ldeH(p + 2);
    u32x4 eLD = ldeL(p + 3), eHD = ldeH(p + 3);
    u32x2 xA = ldx(sA), xB = ldx(sB), xC = ldx(sC), xD = ldx(sD);
    sA = ldsrc(p + 4); sB = ldsrc(p + 5); sC = ldsrc(p + 6); sD = ldsrc(p + 7);

    for (;;) {
        edge_compute(eLA, eHA, xA);
        eLA = ldeL(p + 4); eHA = ldeH(p + 4); xA = ldx(sA); sA = ldsrc(p + 8);
        ++p; if (p == p1) adv();
        if (p >= pend) break;

        edge_compute(eLB, eHB, xB);
        eLB = ldeL(p + 4); eHB = ldeH(p + 4); xB = ldx(sB); sB = ldsrc(p + 8);
        ++p; if (p == p1) adv();
        if (p >= pend) break;

        edge_compute(eLC, eHC, xC);
        eLC = ldeL(p + 4); eHC = ldeH(p + 4); xC = ldx(sC); sC = ldsrc(p + 8);
        ++p; if (p == p1) adv();
        if (p >= pend) break;

        edge_compute(eLD, eHD, xD);
        eLD = ldeL(p + 4); eHD = ldeH(p + 4); xD = ldx(sD); sD = ldsrc(p + 8);
        ++p; if (p == p1) adv();
        if (p >= pend) break;
    }
    // safety: trailing zero-degree nodes (normally handled by adv)
    while (n < nend) { flushv(n, ldx(n)); ++n; }
}

// ---------------------------------------------------------------------------
// gemm_fused v3 (kept from R12, −17 us: frag-packed B). Both GEMMs of a GINE
// layer in one 512-thread kernel: LDS A-tile (XOR 16B-slot swizzle), stage1
// MFMA (Wa frags coalesced) -> BN+relu -> swizzled t tile in LDS, barrier,
// stage2 MFMA (Wb frags) -> bias+relu -> h.
// ---------------------------------------------------------------------------
template<int K>
__global__ __launch_bounds__(512, 4) void gemm_fused(
    const unsigned short* __restrict__ A,    // [M_PAD, K] (u)
    const unsigned short* __restrict__ WaF,  // frag-packed Wa (g,c,half,lane)
    const float* __restrict__ ba,
    const float* __restrict__ gsc, const float* __restrict__ bsh,
    const unsigned short* __restrict__ WbF,  // frag-packed Wb
    const float* __restrict__ bb,
    unsigned short* __restrict__ out)        // [M_PAD, 256] (h)
{
    constexpr int KC1 = K / 32;              // stage1 k-chunks: 4 or 8
    constexpr int KC2 = H / 32;              // stage2 k-chunks: 8
    constexpr int SLOTS = K / 8;             // 16B slots per A row
    __shared__ unsigned short Al[64 * K];    // 16/32 KB
    __shared__ unsigned short Tl[64 * H];    // 32 KB, swizzled slots

    const int w = threadIdx.x >> 6, lane = threadIdx.x & 63;
    const int lm = lane & 15, lq = lane >> 4;
    const int n0 = w * 32;                   // this wave's 32 output cols
    const int m0 = blockIdx.x * 64;

    const bf16x8* Wa8 = (const bf16x8*)WaF;
    const bf16x8* Wb8 = (const bf16x8*)WbF;

    // cooperative A-tile stage (512 threads), XOR-swizzled 16B slots
#pragma unroll
    for (int i = 0; i < 64 * SLOTS / 512; ++i) {
        const int t = i * 512 + threadIdx.x;
        const int row = t / SLOTS, slot = t % SLOTS;
        const uint4 v = *(const uint4*)(A + (size_t)(m0 + row) * K + slot * 8);
        *(uint4*)((char*)Al + row * (K * 2) + ((slot ^ (row & 7)) * 16)) = v;
    }

    const float inv = rsqrtf(1.0f + 1e-5f);
    const float bc0 = ba[n0 + lm],  bc1 = ba[n0 + 16 + lm];
    const float gc0 = gsc[n0 + lm], gc1 = gsc[n0 + 16 + lm];
    const float sc0 = bsh[n0 + lm], sc1 = bsh[n0 + 16 + lm];

    __syncthreads();

    // ---- stage 1: t = relu((u@Wa^T + ba)*inv*g + bt) -> LDS (half-K passes)
    {
        f32x4 acc0[4], acc1[4];
#pragma unroll
        for (int ch = 0; ch < 4; ++ch) {
            acc0[ch] = (f32x4){0.f, 0.f, 0.f, 0.f};
            acc1[ch] = (f32x4){0.f, 0.f, 0.f, 0.f};
        }
#pragma unroll
        for (int kh = 0; kh < KC1; kh += 4) {
            bf16x8 C0[4], C1[4];
#pragma unroll
            for (int c = 0; c < 4; ++c) {
                const int fi = (w * KC1 + kh + c) * 2;
                C0[c] = Wa8[(size_t)(fi + 0) * 64 + lane];
                C1[c] = Wa8[(size_t)(fi + 1) * 64 + lane];
            }
#pragma unroll
            for (int ch = 0; ch < 4; ++ch) {
                const int row = ch * 16 + lm;
                const char* rbase = (const char*)Al + row * (K * 2);
#pragma unroll
                for (int c = 0; c < 4; ++c) {
                    const int slot = (lq + (kh + c) * 4) ^ (row & 7);
                    const bf16x8 a = *(const bf16x8*)(rbase + slot * 16);
                    acc0[ch] = __builtin_amdgcn_mfma_f32_16x16x32_bf16(a, C0[c], acc0[ch], 0, 0, 0);
                    acc1[ch] = __builtin_amdgcn_mfma_f32_16x16x32_bf16(a, C1[c], acc1[ch], 0, 0, 0);
                }
            }
        }
        // write t tile to LDS (bf16, swizzled slots)
#pragma unroll
        for (int ch = 0; ch < 4; ++ch) {
#pragma unroll
            for (int r = 0; r < 4; ++r) {
                const int rowo = ch * 16 + lq * 4 + r;
                const float v0 = fmaxf((acc0[ch][r] + bc0) * inv * gc0 + sc0, 0.0f);
                const float v1 = fmaxf((acc1[ch][r] + bc1) * inv * gc1 + sc1, 0.0f);
                const int col0 = n0 + lm, col1 = n0 + 16 + lm;
                *(unsigned short*)((char*)Tl + rowo * (H * 2)
                    + (((col0 >> 3) ^ (rowo & 7)) << 4) + ((col0 & 7) << 1)) = f2bf(v0);
                *(unsigned short*)((char*)Tl + rowo * (H * 2)
                    + (((col1 >> 3) ^ (rowo & 7)) << 4) + ((col1 & 7) << 1)) = f2bf(v1);
            }
        }
    }

    const float eb0 = bb[n0 + lm], eb1 = bb[n0 + 16 + lm];

    __syncthreads();

    // ---- stage 2: h = relu(t @ Wb^T + bb) (half-K passes)
    {
        f32x4 acc0[4], acc1[4];
#pragma unroll
        for (int ch = 0; ch < 4; ++ch) {
            acc0[ch] = (f32x4){0.f, 0.f, 0.f, 0.f};
            acc1[ch] = (f32x4){0.f, 0.f, 0.f, 0.f};
        }
#pragma unroll
        for (int kh = 0; kh < KC2; kh += 4) {
            bf16x8 C0[4], C1[4];
#pragma unroll
            for (int c = 0; c < 4; ++c) {
                const int fi = (w * KC2 + kh + c) * 2;
                C0[c] = Wb8[(size_t)(fi + 0) * 64 + lane];
                C1[c] = Wb8[(size_t)(fi + 1) * 64 + lane];
            }
#pragma unroll
            for (int ch = 0; ch < 4; ++ch) {
                const int row = ch * 16 + lm;
                const char* rbase = (const char*)Tl + row * (H * 2);
#pragma unroll
                for (int c = 0; c < 4; ++c) {
                    const int slot = (lq + (kh + c) * 4) ^ (row & 7);
                    const bf16x8 a = *(const bf16x8*)(rbase + slot * 16);
                    acc0[ch] = __builtin_amdgcn_mfma_f32_16x16x32_bf16(a, C0[c], acc0[ch], 0, 0, 0);
                    acc1[ch] = __builtin_amdgcn_mfma_f32_16x16x32_bf16(a, C1[c], acc1[ch], 0, 0, 0);
                }
            }
        }
#pragma unroll
        for (int ch = 0; ch < 4; ++ch) {
            const int mr = m0 + ch * 16;
#pragma unroll
            for (int r = 0; r < 4; ++r) {
                const int rowo = mr + lq * 4 + r;
                if (rowo >= N_NODES) continue;
                const float v0 = fmaxf(acc0[ch][r] + eb0, 0.0f);
                const float v1 = fmaxf(acc1[ch][r] + eb1, 0.0f);
                out[(size_t)rowo * H + n0 + lm]      = f2bf(v0);
                out[(size_t)rowo * H + n0 + 16 + lm] = f2bf(v1);
            }
        }
    }
}

// ---------------------------------------------------------------------------
// pool2 v2 (R13 win): u32x4 vectorized loads, 8 rows in flight, LDS
// cross-rowgroup reduce, one atomic per column.
// ---------------------------------------------------------------------------
#define RSPLIT 6
__global__ __launch_bounds__(256) void pool2(
    const unsigned short* __restrict__ h1, const unsigned short* __restrict__ h2,
    const unsigned short* __restrict__ h3, const int* __restrict__ start,
    float* __restrict__ pool)
{
    const int g = blockIdx.x & 63, layer = blockIdx.x >> 6;
    const unsigned short* h = (layer == 0) ? h1 : (layer == 1) ? h2 : h3;
    const int r0 = start[g], r1 = start[g + 1];
    const int nr = r1 - r0;
    if (nr <= 0) return;
    const int chunk = (nr + RSPLIT - 1) / RSPLIT;
    const int rs = r0 + blockIdx.y * chunk;
    const int re = (rs + chunk < r1) ? rs + chunk : r1;
    if (rs >= re) return;

    const int cg = threadIdx.x & 31;         // cols cg*8 .. cg*8+7
    const int rg = threadIdx.x >> 5;         // row group 0..7
    float s0 = 0.f, s1 = 0.f, s2 = 0.f, s3 = 0.f;
    float s4 = 0.f, s5 = 0.f, s6 = 0.f, s7 = 0.f;
    for (int r = rs + rg; r < re; r += 8) {
        const u32x4 v = *(const u32x4*)(h + (size_t)r * H + cg * 8);
        s0 += __builtin_bit_cast(float, v[0] << 16);
        s1 += __builtin_bit_cast(float, v[0] & 0xFFFF0000u);
        s2 += __builtin_bit_cast(float, v[1] << 16);
        s3 += __builtin_bit_cast(float, v[1] & 0xFFFF0000u);
        s4 += __builtin_bit_cast(float, v[2] << 16);
        s5 += __builtin_bit_cast(float, v[2] & 0xFFFF0000u);
        s6 += __builtin_bit_cast(float, v[3] << 16);
        s7 += __builtin_bit_cast(float, v[3] & 0xFFFF0000u);
    }
    __shared__ float red[8][256];
    red[rg][cg * 8 + 0] = s0; red[rg][cg * 8 + 1] = s1;
    red[rg][cg * 8 + 2] = s2; red[rg][cg * 8 + 3] = s3;
    red[rg][cg * 8 + 4] = s4; red[rg][cg * 8 + 5] = s5;
    red[rg][cg * 8 + 6] = s6; red[rg][cg * 8 + 7] = s7;
    __syncthreads();
    float t = 0.f;
#pragma unroll
    for (int q = 0; q < 8; ++q) t += red[q][threadIdx.x];
    atomicAdd(&pool[(size_t)g * POOL_W + layer * 256 + threadIdx.x], t);
}

// ---------------------------------------------------------------------------
// fc_head v3 (R13 win): two graphs per block — each L1w fragment loaded once
// and dotted against both p-vectors. Grid (32, 12).
// ---------------------------------------------------------------------------
__global__ __launch_bounds__(256) void fc_head(
    const float* __restrict__ pool, const int* __restrict__ start,
    const float* __restrict__ L1w, const float* __restrict__ L1b,
    const float* __restrict__ L2w, float* __restrict__ gsum)
{
    const int g0 = blockIdx.x * 2, g1 = g0 + 1;
    __shared__ float p[2][POOL_W];

    const float rc0 = 1.0f / fmaxf((float)(start[g0 + 1] - start[g0]), 1.0f);
    const float rc1 = 1.0f / fmaxf((float)(start[g1 + 1] - start[g1]), 1.0f);
    for (int i = threadIdx.x; i < POOL_W; i += 256) {
        p[0][i] = pool[(size_t)g0 * POOL_W + i] * rc0;
        p[1][i] = pool[(size_t)g1 * POOL_W + i] * rc1;
    }
    __syncthreads();

    const int wv = threadIdx.x >> 6, lane = threadIdx.x & 63;
    const float4* pA = (const float4*)p[0];
    const float4* pB = (const float4*)p[1];
    const float4 a0 = pA[lane], a1 = pA[lane + 64], a2 = pA[lane + 128];
    const float4 b0 = pB[lane], b1 = pB[lane + 64], b2 = pB[lane + 128];

    const int ob = blockIdx.y * 64 + wv * 16;
    float part0 = 0.0f, part1 = 0.0f;
#pragma unroll 4
    for (int t = 0; t < 16; ++t) {
        const int o = ob + t;
        const float4* wr = (const float4*)(L1w + (size_t)o * POOL_W);
        const float4 wa = wr[lane], wb = wr[lane + 64], wc = wr[lane + 128];
        float accA = wa.x * a0.x + wa.y * a0.y + wa.z * a0.z + wa.w * a0.w
                   + wb.x * a1.x + wb.y * a1.y + wb.z * a1.z + wb.w * a1.w
                   + wc.x * a2.x + wc.y * a2.y + wc.z * a2.z + wc.w * a2.w;
        float accB = wa.x * b0.x + wa.y * b0.y + wa.z * b0.z + wa.w * b0.w
                   + wb.x * b1.x + wb.y * b1.y + wb.z * b1.z + wb.w * b1.w
                   + wc.x * b2.x + wc.y * b2.y + wc.z * b2.z + wc.w * b2.w;
#pragma unroll
        for (int off = 32; off > 0; off >>= 1) {
            accA += __shfl_xor(accA, off);
            accB += __shfl_xor(accB, off);
        }
        if (lane == 0) {
            const float r = fmaxf(accA + L1b[o], 0.0f);
            const float s = fmaxf(accB + L1b[o], 0.0f);
            part0 += r * L2w[o];
            part1 += s * L2w[o];
        }
    }
    if (lane == 0) {
        atomicAdd(&gsum[g0], part0);
        atomicAdd(&gsum[g1], part1);
    }
}

__global__ __launch_bounds__(64) void sig_kernel(
    const float* __restrict__ gsum, const float* __restrict__ L2b,
    float* __restrict__ out)
{
    const int g = threadIdx.x;
    if (g < N_GRAPHS) out[g] = 1.0f / (1.0f + expf(-(gsum[g] + L2b[0])));
}

// ---------------------------------------------------------------------------
extern "C" void kernel_launch(void* const* d_in, const int* in_sizes, int n_in,
                              void* d_out, int out_size, void* d_ws, size_t ws_size,
                              hipStream_t stream)
{
    const float* x     = (const float*)d_in[0];
    const float* ea    = (const float*)d_in[1];
    const int*   src   = (const int*)d_in[2];
    const int*   dst   = (const int*)d_in[3];
    const int*   batch = (const int*)d_in[4];

    const float* We[3]; const float* be[3]; const float* Wa[3]; const float* ba[3];
    const float* gg[3]; const float* bt[3]; const float* Wb[3]; const float* bb[3];
    for (int l = 0; l < 3; ++l) {
        const int o = 5 + 8 * l;
        We[l] = (const float*)d_in[o + 0]; be[l] = (const float*)d_in[o + 1];
        Wa[l] = (const float*)d_in[o + 2]; ba[l] = (const float*)d_in[o + 3];
        gg[l] = (const float*)d_in[o + 4]; bt[l] = (const float*)d_in[o + 5];
        Wb[l] = (const float*)d_in[o + 6]; bb[l] = (const float*)d_in[o + 7];
    }
    const float* L1w = (const float*)d_in[29];
    const float* L1b = (const float*)d_in[30];
    const float* L2w = (const float*)d_in[31];
    const float* L2b = (const float*)d_in[32];

    // ---- workspace layout ----
    float* pool   = (float*)d_ws;                              // 64*768
    float* gsum   = pool + (size_t)N_GRAPHS * POOL_W;          // 64 (zeroed with pool)
    int*   deg    = (int*)(gsum + N_GRAPHS);                   // N
    int*   off    = deg + N_NODES;                             // N+1
    int*   cursor = off + N_NODES + 1;                         // N
    int*   start  = cursor + N_NODES;                          // 72
    int*   cmap   = start + 72;                                // NCHUNK+1
    int*   ssrc   = (int*)((((uintptr_t)(cmap + NCHUNK + 1)) + 31) & ~(uintptr_t)31);  // E+16 ints, CSR
    unsigned short* eas = (unsigned short*)((((uintptr_t)(ssrc + N_EDGES + 16)) + 31) & ~(uintptr_t)31); // [E+16,16] f16 CSR
    unsigned short* xb = (unsigned short*)((((uintptr_t)(eas + (size_t)(N_EDGES + 16) * 16)) + 31) & ~(uintptr_t)31);
    unsigned short* u  = xb + (size_t)M_PAD * DIN;             // [M_PAD,256] (layer1 uses 128)
    unsigned short* h1 = u  + (size_t)M_PAD * H;
    unsigned short* h2 = h1 + (size_t)M_PAD * H;
    unsigned short* h3 = h2 + (size_t)M_PAD * H;
    unsigned short* wbf[6];
    wbf[0] = h3 + (size_t)M_PAD * H;                           // Wa1 frag [256,128]
    wbf[1] = wbf[0] + H * DIN;
    for (int i = 2; i < 6; ++i) wbf[i] = wbf[i - 1] + H * H;
    unsigned short* weh[3];
    weh[0] = wbf[5] + H * H;                                   // We1 [128,16] f16
    weh[1] = weh[0] + DIN * 16;                                // We2 [256,16] f16
    weh[2] = weh[1] + H * 16;                                  // We3 [256,16] f16

    // batched converts + deg/pool+gsum zeroing in one launch (12 jobs)
    CvtJobs jobs;
    jobs.j[0]  = { x,       xb,                    N_NODES * DIN / 4,       0, 0 };
    jobs.j[1]  = { Wa[0],   wbf[0],                H * DIN / 8,             3, DIN };
    jobs.j[2]  = { Wb[0],   wbf[1],                H * H / 8,               3, H };
    jobs.j[3]  = { Wa[1],   wbf[2],                H * H / 8,               3, H };
    jobs.j[4]  = { Wb[1],   wbf[3],                H * H / 8,               3, H };
    jobs.j[5]  = { Wa[2],   wbf[4],                H * H / 8,               3, H };
    jobs.j[6]  = { Wb[2],   wbf[5],                H * H / 8,               3, H };
    jobs.j[7]  = { nullptr, (unsigned short*)deg,  N_NODES * 4 / 8,         2, 0 };  // zero N ints
    jobs.j[8]  = { nullptr, (unsigned short*)pool, (N_GRAPHS * POOL_W + N_GRAPHS) * 4 / 8, 2, 0 }; // zero pool+gsum
    jobs.j[9]  = { We[0],   weh[0],                DIN * 16 / 4,            1, 0 };
    jobs.j[10] = { We[1],   weh[1],                H * 16 / 4,              1, 0 };
    jobs.j[11] = { We[2],   weh[2],                H * 16 / 4,              1, 0 };
    cvt_all<<<dim3(320, 12), 256, 0, stream>>>(jobs);

    // CSR + graph boundaries; scatter also computes the chunk map (merged)
    hist_kernel<<<EDGE_BLOCKS, 256, 0, stream>>>(dst, deg);
    scan_kernel<<<1, 1024, 0, stream>>>(deg, off, cursor, batch, start);
    scatter_kernel<<<EDGE_BLOCKS + CMAP_BLOCKS, 256, 0, stream>>>(
        src, dst, ea, cursor, ssrc, eas, off, cmap);

    const int agrid = NCHUNK / 4;               // agg3: 1 chunk/wave, 4 waves/block
    const int ggrid = M_PAD / 64;               // gemm_fused: 313 blocks x 512

    // ---- layer 1 (in=128) ----
    agg3<DIN><<<agrid, 256, 0, stream>>>(xb, eas, ssrc, off, cmap, weh[0], be[0], u);
    gemm_fused<DIN><<<ggrid, 512, 0, stream>>>(u, wbf[0], ba[0], gg[0], bt[0], wbf[1], bb[0], h1);
    // ---- layer 2 ----
    agg3<H><<<agrid, 256, 0, stream>>>(h1, eas, ssrc, off, cmap, weh[1], be[1], u);
    gemm_fused<H><<<ggrid, 512, 0, stream>>>(u, wbf[2], ba[1], gg[1], bt[1], wbf[3], bb[1], h2);
    // ---- layer 3 ----
    agg3<H><<<agrid, 256, 0, stream>>>(h2, eas, ssrc, off, cmap, weh[2], be[2], u);
    gemm_fused<H><<<ggrid, 512, 0, stream>>>(u, wbf[4], ba[2], gg[2], bt[2], wbf[5], bb[2], h3);

    // parallel mean-pool + head (fc_head: 2 graphs/block)
    pool2<<<dim3(3 * N_GRAPHS, RSPLIT), 256, 0, stream>>>(h1, h2, h3, start, pool);
    fc_head<<<dim3(N_GRAPHS / 2, POOL_W / 64), 256, 0, stream>>>(pool, start, L1w, L1b, L2w, gsum);
    sig_kernel<<<1, 64, 0, stream>>>(gsum, L2b, (float*)d_out);
}

// Round 17
// 441.464 us; speedup vs baseline: 1.1669x; 1.0047x over previous
//
#include <hip/hip_runtime.h>
#include <math.h>
#include <stdint.h>

#define N_NODES 20000
#define M_PAD 20032            // 313 * 64
#define N_EDGES 320000
#define N_GRAPHS 64
#define DIN 128
#define H 256
#define POOL_W 768
#define CHUNK 40               // edges per wave in agg3
#define NCHUNK (N_EDGES / CHUNK)   // 8000 (exact)
#define EDGE_BLOCKS ((N_EDGES + 255) / 256)    // 1250
#define CMAP_BLOCKS ((NCHUNK + 1 + 255) / 256) // 32

typedef __attribute__((ext_vector_type(8))) short bf16x8;   // 8 bf16 = 4 VGPRs
typedef __attribute__((ext_vector_type(4))) float f32x4;
typedef __attribute__((ext_vector_type(4))) unsigned int u32x4;
typedef __attribute__((ext_vector_type(2))) unsigned int u32x2;
typedef _Float16 h2 __attribute__((ext_vector_type(2)));    // packed f16 pair (1 VGPR)

__device__ __forceinline__ unsigned short f2bf(float f) {
    unsigned u = __builtin_bit_cast(unsigned, f);
    u += 0x7FFFu + ((u >> 16) & 1u);          // round-to-nearest-even
    return (unsigned short)(u >> 16);
}
__device__ __forceinline__ float bf2f(unsigned short u) {
    return __builtin_bit_cast(float, (unsigned)u << 16);
}
__device__ __forceinline__ unsigned short f2h(float f) {
    const _Float16 h = (_Float16)f;
    return __builtin_bit_cast(unsigned short, h);
}

#if __has_builtin(__builtin_amdgcn_fdot2)
#define DOT2(a, b, c) __builtin_amdgcn_fdot2((a), (b), (c), false)
#else
__device__ __forceinline__ float dot2_fallback(h2 a, h2 b, float c) {
    return fmaf((float)a.x, (float)b.x, fmaf((float)a.y, (float)b.y, c));
}
#define DOT2(a, b, c) dot2_fallback((a), (b), (c))
#endif

// ---------------------------------------------------------------------------
// Batched converts + zero jobs: 12 jobs, one launch.
// mode 0: fp32 -> bf16 row-major     mode 1: fp32 -> f16
// mode 2: zero fill                  mode 3: fp32 W[256][K] -> MFMA-fragment
// ---------------------------------------------------------------------------
struct CvtJob  { const float* s; unsigned short* d; int n4; int mode; int kdim; };
struct CvtJobs { CvtJob j[12]; };

__global__ __launch_bounds__(256) void cvt_all(CvtJobs jobs)
{
    const CvtJob J = jobs.j[blockIdx.y];
    if (J.mode == 2) {
        const ushort4 z = {0, 0, 0, 0};
        for (int i = blockIdx.x * 256 + threadIdx.x; i < J.n4; i += gridDim.x * 256)
            ((ushort4*)J.d)[i] = z;
        return;
    }
    if (J.mode == 1) {
        for (int i = blockIdx.x * 256 + threadIdx.x; i < J.n4; i += gridDim.x * 256) {
            const float4 v = ((const float4*)J.s)[i];
            ushort4 r;
            r.x = f2h(v.x); r.y = f2h(v.y); r.z = f2h(v.z); r.w = f2h(v.w);
            ((ushort4*)J.d)[i] = r;
        }
        return;
    }
    if (J.mode == 3) {
        const int K = J.kdim, KC = K / 32;
        for (int t = blockIdx.x * 256 + threadIdx.x; t < J.n4; t += gridDim.x * 256) {
            int unit = t;
            const int lane = unit & 63; unit >>= 6;
            const int half = unit & 1;  unit >>= 1;
            const int c = unit % KC;
            const int g = unit / KC;
            const int row = g * 32 + half * 16 + (lane & 15);
            const int kb  = c * 32 + ((lane >> 4) << 3);
            const float4 v0 = *(const float4*)(J.s + (size_t)row * K + kb);
            const float4 v1 = *(const float4*)(J.s + (size_t)row * K + kb + 4);
            ushort4 r0, r1;
            r0.x = f2bf(v0.x); r0.y = f2bf(v0.y); r0.z = f2bf(v0.z); r0.w = f2bf(v0.w);
            r1.x = f2bf(v1.x); r1.y = f2bf(v1.y); r1.z = f2bf(v1.z); r1.w = f2bf(v1.w);
            ushort4* dst = (ushort4*)(J.d + (size_t)t * 8);
            dst[0] = r0; dst[1] = r1;
        }
        return;
    }
    for (int i = blockIdx.x * 256 + threadIdx.x; i < J.n4; i += gridDim.x * 256) {
        const float4 v = ((const float4*)J.s)[i];
        ushort4 r;
        r.x = f2bf(v.x); r.y = f2bf(v.y); r.z = f2bf(v.z); r.w = f2bf(v.w);
        ((ushort4*)J.d)[i] = r;
    }
}

// ---------------------------------------------------------------------------
// CSR build
// ---------------------------------------------------------------------------
__global__ __launch_bounds__(256) void hist_kernel(const int* __restrict__ dst,
                                                   int* __restrict__ deg)
{
    const int i = blockIdx.x * 256 + threadIdx.x;
    if (i < N_EDGES) atomicAdd(deg + dst[i], 1);
}

// shfl scan; writes off and cursor; tail threads also compute graph starts.
__global__ __launch_bounds__(1024) void scan_kernel(const int* __restrict__ deg,
                                                    int* __restrict__ off,
                                                    int* __restrict__ cur,
                                                    const int* __restrict__ batch,
                                                    int* __restrict__ start)
{
    __shared__ int wsum[16];
    __shared__ int carry;
    const int tid = threadIdx.x, wave = tid >> 6, lane = tid & 63;
    if (tid == 0) carry = 0;
    __syncthreads();
    for (int base = 0; base < N_NODES; base += 1024) {
        const int i = base + tid;
        const int v = (i < N_NODES) ? deg[i] : 0;
        int s = v;
#pragma unroll
        for (int d = 1; d < 64; d <<= 1) {
            const int t = __shfl_up(s, d);
            if (lane >= d) s += t;
        }
        if (lane == 63) wsum[wave] = s;
        __syncthreads();
        if (wave == 0) {
            int t = (lane < 16) ? wsum[lane] : 0;
#pragma unroll
            for (int d = 1; d < 16; d <<= 1) {
                const int u = __shfl_up(t, d);
                if (lane >= d) t += u;
            }
            if (lane < 16) wsum[lane] = t;
        }
        __syncthreads();
        const int wbase = (wave == 0) ? 0 : wsum[wave - 1];
        if (i < N_NODES) {
            const int o = carry + wbase + s - v;
            off[i] = o;
            cur[i] = o;
        }
        const int tot = wsum[15];
        __syncthreads();
        if (tid == 0) carry += tot;
        __syncthreads();
    }
    if (tid == 0) off[N_NODES] = carry;

    // graph boundaries (batch is sorted)
    if (tid <= N_GRAPHS) {
        if (tid == N_GRAPHS) { start[N_GRAPHS] = N_NODES; }
        else {
            int lo = 0, hi = N_NODES;
            while (lo < hi) { const int mid = (lo + hi) >> 1; if (batch[mid] < tid) lo = mid + 1; else hi = mid; }
            start[tid] = lo;
        }
    }
}

// scatter v4: edge blocks build CSR-sorted (src, ea_f16); trailing 32 blocks
// compute the chunk->node map (block-parallel — R9 lesson) AND zero the
// 16-entry ssrc pad (pad entries are loaded by agg3's pipeline and
// dereferenced as node ids — must be valid; node 0 is always valid).
__global__ __launch_bounds__(256) void scatter_kernel(
    const int* __restrict__ src, const int* __restrict__ dst,
    const float* __restrict__ ea, int* __restrict__ cursor,
    int* __restrict__ ssrc, unsigned short* __restrict__ eas,
    const int* __restrict__ off, int* __restrict__ cmap)
{
    if (blockIdx.x >= EDGE_BLOCKS) {         // chunkmap + pad part
        const int w = (blockIdx.x - EDGE_BLOCKS) * 256 + threadIdx.x;
        if (w < 16) ssrc[N_EDGES + w] = 0;   // init pad (valid node id)
        if (w > NCHUNK) return;
        if (w == NCHUNK) { cmap[w] = N_NODES; return; }
        const int target = w * CHUNK;
        int lo = 0, hi = N_NODES;            // first n with off[n] >= target
        while (lo < hi) { const int mid = (lo + hi) >> 1; if (off[mid] < target) lo = mid + 1; else hi = mid; }
        cmap[w] = lo;
        return;
    }
    const int e = blockIdx.x * 256 + threadIdx.x;
    if (e < N_EDGES) {
        const int p = atomicAdd(cursor + dst[e], 1);
        ssrc[p] = src[e];
        const float4* er = (const float4*)(ea + (size_t)e * 16);
        ushort4* d4 = (ushort4*)(eas + (size_t)p * 16);
#pragma unroll
        for (int q = 0; q < 4; ++q) {
            const float4 v = er[q];
            ushort4 r;
            r.x = f2h(v.x); r.y = f2h(v.y); r.z = f2h(v.z); r.w = f2h(v.w);
            d4[q] = r;
        }
    }
}

// ---------------------------------------------------------------------------
// agg3 v9 — R13 structure (measured best, 67 us, VGPR 44) with the per-edge
// ADDRESS ARITHMETIC strength-reduced: eas and ssrc walk linearly, so the
// per-edge 64-bit address recomputation ((p+4)*16 muls, ~10-12 VALU/edge)
// is replaced by two incrementing pointers (pe += 2 u32x4, ps += 1). The
// ssrc clamp is deleted (pad is now initialized by scatter). zd is folded
// into the pointer BASES once — keeps them divergent (VMEM, not SMEM) per
// the R1 scalarization lesson. Skeleton, flush logic, launch bounds
// unchanged (R15 lesson: launch_bounds is a register cap, not a hint).
// out[v] = bf16( x[v] + sum_e relu(x[src] + ea@We.T + be) )
// ---------------------------------------------------------------------------
template<int IN>
__global__ __launch_bounds__(256, 4) void agg3(
    const unsigned short* __restrict__ xb,   // [M_PAD, IN] bf16
    const unsigned short* __restrict__ eas,  // [E+16,16] f16, CSR order
    const int* __restrict__ ssrc,            // [E+16] src, CSR order (pad=0)
    const int* __restrict__ off,             // [N+1]
    const int* __restrict__ cmap,            // [NCHUNK+1]
    const unsigned short* __restrict__ Weh,  // [IN,16] f16
    const float* __restrict__ be,
    unsigned short* __restrict__ out)        // [M_PAD, IN] bf16
{
    constexpr int CPL = IN / 64;             // 2 (layer1) or 4
    constexpr int XW  = CPL / 2;             // x-row dwords per lane: 1 or 2
    const int lane = threadIdx.x & 63;
    const int wid  = blockIdx.x * 4 + (threadIdx.x >> 6);
    const int c0 = lane * CPL;
    const int zd = __builtin_amdgcn_mbcnt_lo(0u, 0u);   // divergent zero: defeats SMEM scalarization

    // weights: CPL rows x 16 f16 — loaded once, best-effort pinned
    u32x4 wlo[CPL], whi[CPL];
    float bias[CPL], acc[CPL];
#pragma unroll
    for (int j = 0; j < CPL; ++j) {
        const u32x4* wr = (const u32x4*)(Weh + (size_t)(c0 + j) * 16);
        wlo[j] = wr[0];
        whi[j] = wr[1];
        bias[j] = be[c0 + j];
        acc[j]  = 0.0f;
    }
#pragma unroll
    for (int j = 0; j < CPL; ++j) {
#pragma unroll
        for (int k = 0; k < 4; ++k) {
            { float t = __builtin_bit_cast(float, wlo[j][k]); asm volatile("" : "+v"(t)); wlo[j][k] = __builtin_bit_cast(unsigned int, t); }
            { float t = __builtin_bit_cast(float, whi[j][k]); asm volatile("" : "+v"(t)); whi[j][k] = __builtin_bit_cast(unsigned int, t); }
        }
        asm volatile("" : "+v"(bias[j]));
    }

    int n          = __builtin_amdgcn_readfirstlane(cmap[wid]);
    const int nend = __builtin_amdgcn_readfirstlane(cmap[wid + 1]);
    if (n >= nend) return;                    // giant node spans this chunk
    int p          = __builtin_amdgcn_readfirstlane(off[n]);
    const int pend = __builtin_amdgcn_readfirstlane(off[nend]);

    auto ldx = [&](int s) -> u32x2 {          // row of xb (src gather or self)
        if constexpr (XW == 2) {
            return *(const u32x2*)(xb + (size_t)s * IN + c0);
        } else {
            u32x2 r;
            r[0] = *(const unsigned int*)(xb + (size_t)s * IN + c0);
            r[1] = 0u;
            return r;
        }
    };
    auto flushv = [&](int nn, u32x2 xs) {     // store bf16(x[nn] + acc); acc = 0
        if constexpr (XW == 2) {
            const float x0 = __builtin_bit_cast(float, xs[0] << 16);
            const float x1 = __builtin_bit_cast(float, xs[0] & 0xFFFF0000u);
            const float x2 = __builtin_bit_cast(float, xs[1] << 16);
            const float x3 = __builtin_bit_cast(float, xs[1] & 0xFFFF0000u);
            u32x2 o;
            o[0] = (unsigned)f2bf(x0 + acc[0]) | ((unsigned)f2bf(x1 + acc[1]) << 16);
            o[1] = (unsigned)f2bf(x2 + acc[2]) | ((unsigned)f2bf(x3 + acc[3]) << 16);
            *(u32x2*)(out + (size_t)nn * IN + c0) = o;
        } else {
            const float x0 = __builtin_bit_cast(float, xs[0] << 16);
            const float x1 = __builtin_bit_cast(float, xs[0] & 0xFFFF0000u);
            const unsigned int o =
                (unsigned)f2bf(x0 + acc[0]) | ((unsigned)f2bf(x1 + acc[1]) << 16);
            *(unsigned int*)(out + (size_t)nn * IN + c0) = o;
        }
#pragma unroll
        for (int j = 0; j < CPL; ++j) acc[j] = 0.0f;
    };

    // zero-degree nodes at the head of the range (immediate x loads — rare)
    int p1 = __builtin_amdgcn_readfirstlane(off[n + 1]);
    while (p1 == p) {
        flushv(n, ldx(n)); ++n;
        if (n >= nend) return;
        p1 = __builtin_amdgcn_readfirstlane(off[n + 1]);
    }
    // here: current node n non-empty, p = off[n] < p1 <= pend
    u32x2 xself = ldx(n);                     // prefetched; consumed at flush

    auto edge_compute = [&](u32x4 eL, u32x4 eH, u32x2 xw) {
        float m[CPL];
#pragma unroll
        for (int j = 0; j < CPL; ++j) m[j] = bias[j];
#pragma unroll
        for (int k = 0; k < 4; ++k) {
            const h2 ep = __builtin_bit_cast(h2, eL[k]);
#pragma unroll
            for (int j = 0; j < CPL; ++j)
                m[j] = DOT2(ep, __builtin_bit_cast(h2, wlo[j][k]), m[j]);
        }
#pragma unroll
        for (int k = 0; k < 4; ++k) {
            const h2 ep = __builtin_bit_cast(h2, eH[k]);
#pragma unroll
            for (int j = 0; j < CPL; ++j)
                m[j] = DOT2(ep, __builtin_bit_cast(h2, whi[j][k]), m[j]);
        }
#pragma unroll
        for (int j = 0; j < CPL; ++j) {
            const unsigned int word = xw[j >> 1];
            const float xf = __builtin_bit_cast(float,
                (j & 1) ? (word & 0xFFFF0000u) : (word << 16));
            acc[j] += fmaxf(m[j] + xf, 0.0f);
        }
    };
    // flush current node (prefetched xself) + zero-degree ties; prefetch next
    auto adv = [&]() {
        flushv(n, xself); ++n;
        while (n < nend) {
            p1 = __builtin_amdgcn_readfirstlane(off[n + 1]);
            if (p1 != p) { xself = ldx(n); break; }
            flushv(n, ldx(n)); ++n;           // zero-degree tie: immediate (rare)
        }
    };

    // incrementing divergent edge-stream pointers (zd folded into base once)
    const u32x4* pe = (const u32x4*)eas + ((size_t)(p + zd)) * 2;  // 2 u32x4/row
    const int*   ps = ssrc + p + zd;

    // depth-4 pipeline, in-place buffers, runs across node boundaries
    int sA = ps[0], sB = ps[1], sC = ps[2], sD = ps[3];
    u32x4 eLA = pe[0], eHA = pe[1];
    u32x4 eLB = pe[2], eHB = pe[3];
    u32x4 eLC = pe[4], eHC = pe[5];
    u32x4 eLD = pe[6], eHD = pe[7];
    u32x2 xA = ldx(sA), xB = ldx(sB), xC = ldx(sC), xD = ldx(sD);
    sA = ps[4]; sB = ps[5]; sC = ps[6]; sD = ps[7];

    for (;;) {
        edge_compute(eLA, eHA, xA);
        eLA = pe[8]; eHA = pe[9]; xA = ldx(sA); sA = ps[8];
        pe += 2; ++ps;
        ++p; if (p == p1) adv();
        if (p >= pend) break;

        edge_compute(eLB, eHB, xB);
        eLB = pe[8]; eHB = pe[9]; xB = ldx(sB); sB = ps[8];
        pe += 2; ++ps;
        ++p; if (p == p1) adv();
        if (p >= pend) break;

        edge_compute(eLC, eHC, xC);
        eLC = pe[8]; eHC = pe[9]; xC = ldx(sC); sC = ps[8];
        pe += 2; ++ps;
        ++p; if (p == p1) adv();
        if (p >= pend) break;

        edge_compute(eLD, eHD, xD);
        eLD = pe[8]; eHD = pe[9]; xD = ldx(sD); sD = ps[8];
        pe += 2; ++ps;
        ++p; if (p == p1) adv();
        if (p >= pend) break;
    }
    // safety: trailing zero-degree nodes (normally handled by adv)
    while (n < nend) { flushv(n, ldx(n)); ++n; }
}

// ---------------------------------------------------------------------------
// gemm_fused v3 (kept from R12, −17 us: frag-packed B). Both GEMMs of a GINE
// layer in one 512-thread kernel: LDS A-tile (XOR 16B-slot swizzle), stage1
// MFMA (Wa frags coalesced) -> BN+relu -> swizzled t tile in LDS, barrier,
// stage2 MFMA (Wb frags) -> bias+relu -> h.
// ---------------------------------------------------------------------------
template<int K>
__global__ __launch_bounds__(512, 4) void gemm_fused(
    const unsigned short* __restrict__ A,    // [M_PAD, K] (u)
    const unsigned short* __restrict__ WaF,  // frag-packed Wa (g,c,half,lane)
    const float* __restrict__ ba,
    const float* __restrict__ gsc, const float* __restrict__ bsh,
    const unsigned short* __restrict__ WbF,  // frag-packed Wb
    const float* __restrict__ bb,
    unsigned short* __restrict__ out)        // [M_PAD, 256] (h)
{
    constexpr int KC1 = K / 32;              // stage1 k-chunks: 4 or 8
    constexpr int KC2 = H / 32;              // stage2 k-chunks: 8
    constexpr int SLOTS = K / 8;             // 16B slots per A row
    __shared__ unsigned short Al[64 * K];    // 16/32 KB
    __shared__ unsigned short Tl[64 * H];    // 32 KB, swizzled slots

    const int w = threadIdx.x >> 6, lane = threadIdx.x & 63;
    const int lm = lane & 15, lq = lane >> 4;
    const int n0 = w * 32;                   // this wave's 32 output cols
    const int m0 = blockIdx.x * 64;

    const bf16x8* Wa8 = (const bf16x8*)WaF;
    const bf16x8* Wb8 = (const bf16x8*)WbF;

    // cooperative A-tile stage (512 threads), XOR-swizzled 16B slots
#pragma unroll
    for (int i = 0; i < 64 * SLOTS / 512; ++i) {
        const int t = i * 512 + threadIdx.x;
        const int row = t / SLOTS, slot = t % SLOTS;
        const uint4 v = *(const uint4*)(A + (size_t)(m0 + row) * K + slot * 8);
        *(uint4*)((char*)Al + row * (K * 2) + ((slot ^ (row & 7)) * 16)) = v;
    }

    const float inv = rsqrtf(1.0f + 1e-5f);
    const float bc0 = ba[n0 + lm],  bc1 = ba[n0 + 16 + lm];
    const float gc0 = gsc[n0 + lm], gc1 = gsc[n0 + 16 + lm];
    const float sc0 = bsh[n0 + lm], sc1 = bsh[n0 + 16 + lm];

    __syncthreads();

    // ---- stage 1: t = relu((u@Wa^T + ba)*inv*g + bt) -> LDS (half-K passes)
    {
        f32x4 acc0[4], acc1[4];
#pragma unroll
        for (int ch = 0; ch < 4; ++ch) {
            acc0[ch] = (f32x4){0.f, 0.f, 0.f, 0.f};
            acc1[ch] = (f32x4){0.f, 0.f, 0.f, 0.f};
        }
#pragma unroll
        for (int kh = 0; kh < KC1; kh += 4) {
            bf16x8 C0[4], C1[4];
#pragma unroll
            for (int c = 0; c < 4; ++c) {
                const int fi = (w * KC1 + kh + c) * 2;
                C0[c] = Wa8[(size_t)(fi + 0) * 64 + lane];
                C1[c] = Wa8[(size_t)(fi + 1) * 64 + lane];
            }
#pragma unroll
            for (int ch = 0; ch < 4; ++ch) {
                const int row = ch * 16 + lm;
                const char* rbase = (const char*)Al + row * (K * 2);
#pragma unroll
                for (int c = 0; c < 4; ++c) {
                    const int slot = (lq + (kh + c) * 4) ^ (row & 7);
                    const bf16x8 a = *(const bf16x8*)(rbase + slot * 16);
                    acc0[ch] = __builtin_amdgcn_mfma_f32_16x16x32_bf16(a, C0[c], acc0[ch], 0, 0, 0);
                    acc1[ch] = __builtin_amdgcn_mfma_f32_16x16x32_bf16(a, C1[c], acc1[ch], 0, 0, 0);
                }
            }
        }
        // write t tile to LDS (bf16, swizzled slots)
#pragma unroll
        for (int ch = 0; ch < 4; ++ch) {
#pragma unroll
            for (int r = 0; r < 4; ++r) {
                const int rowo = ch * 16 + lq * 4 + r;
                const float v0 = fmaxf((acc0[ch][r] + bc0) * inv * gc0 + sc0, 0.0f);
                const float v1 = fmaxf((acc1[ch][r] + bc1) * inv * gc1 + sc1, 0.0f);
                const int col0 = n0 + lm, col1 = n0 + 16 + lm;
                *(unsigned short*)((char*)Tl + rowo * (H * 2)
                    + (((col0 >> 3) ^ (rowo & 7)) << 4) + ((col0 & 7) << 1)) = f2bf(v0);
                *(unsigned short*)((char*)Tl + rowo * (H * 2)
                    + (((col1 >> 3) ^ (rowo & 7)) << 4) + ((col1 & 7) << 1)) = f2bf(v1);
            }
        }
    }

    const float eb0 = bb[n0 + lm], eb1 = bb[n0 + 16 + lm];

    __syncthreads();

    // ---- stage 2: h = relu(t @ Wb^T + bb) (half-K passes)
    {
        f32x4 acc0[4], acc1[4];
#pragma unroll
        for (int ch = 0; ch < 4; ++ch) {
            acc0[ch] = (f32x4){0.f, 0.f, 0.f, 0.f};
            acc1[ch] = (f32x4){0.f, 0.f, 0.f, 0.f};
        }
#pragma unroll
        for (int kh = 0; kh < KC2; kh += 4) {
            bf16x8 C0[4], C1[4];
#pragma unroll
            for (int c = 0; c < 4; ++c) {
                const int fi = (w * KC2 + kh + c) * 2;
                C0[c] = Wb8[(size_t)(fi + 0) * 64 + lane];
                C1[c] = Wb8[(size_t)(fi + 1) * 64 + lane];
            }
#pragma unroll
            for (int ch = 0; ch < 4; ++ch) {
                const int row = ch * 16 + lm;
                const char* rbase = (const char*)Tl + row * (H * 2);
#pragma unroll
                for (int c = 0; c < 4; ++c) {
                    const int slot = (lq + (kh + c) * 4) ^ (row & 7);
                    const bf16x8 a = *(const bf16x8*)(rbase + slot * 16);
                    acc0[ch] = __builtin_amdgcn_mfma_f32_16x16x32_bf16(a, C0[c], acc0[ch], 0, 0, 0);
                    acc1[ch] = __builtin_amdgcn_mfma_f32_16x16x32_bf16(a, C1[c], acc1[ch], 0, 0, 0);
                }
            }
        }
#pragma unroll
        for (int ch = 0; ch < 4; ++ch) {
            const int mr = m0 + ch * 16;
#pragma unroll
            for (int r = 0; r < 4; ++r) {
                const int rowo = mr + lq * 4 + r;
                if (rowo >= N_NODES) continue;
                const float v0 = fmaxf(acc0[ch][r] + eb0, 0.0f);
                const float v1 = fmaxf(acc1[ch][r] + eb1, 0.0f);
                out[(size_t)rowo * H + n0 + lm]      = f2bf(v0);
                out[(size_t)rowo * H + n0 + 16 + lm] = f2bf(v1);
            }
        }
    }
}

// ---------------------------------------------------------------------------
// pool2 v2 (R13 win): u32x4 vectorized loads, 8 rows in flight, LDS
// cross-rowgroup reduce, one atomic per column.
// ---------------------------------------------------------------------------
#define RSPLIT 6
__global__ __launch_bounds__(256) void pool2(
    const unsigned short* __restrict__ h1, const unsigned short* __restrict__ h2,
    const unsigned short* __restrict__ h3, const int* __restrict__ start,
    float* __restrict__ pool)
{
    const int g = blockIdx.x & 63, layer = blockIdx.x >> 6;
    const unsigned short* h = (layer == 0) ? h1 : (layer == 1) ? h2 : h3;
    const int r0 = start[g], r1 = start[g + 1];
    const int nr = r1 - r0;
    if (nr <= 0) return;
    const int chunk = (nr + RSPLIT - 1) / RSPLIT;
    const int rs = r0 + blockIdx.y * chunk;
    const int re = (rs + chunk < r1) ? rs + chunk : r1;
    if (rs >= re) return;

    const int cg = threadIdx.x & 31;         // cols cg*8 .. cg*8+7
    const int rg = threadIdx.x >> 5;         // row group 0..7
    float s0 = 0.f, s1 = 0.f, s2 = 0.f, s3 = 0.f;
    float s4 = 0.f, s5 = 0.f, s6 = 0.f, s7 = 0.f;
    for (int r = rs + rg; r < re; r += 8) {
        const u32x4 v = *(const u32x4*)(h + (size_t)r * H + cg * 8);
        s0 += __builtin_bit_cast(float, v[0] << 16);
        s1 += __builtin_bit_cast(float, v[0] & 0xFFFF0000u);
        s2 += __builtin_bit_cast(float, v[1] << 16);
        s3 += __builtin_bit_cast(float, v[1] & 0xFFFF0000u);
        s4 += __builtin_bit_cast(float, v[2] << 16);
        s5 += __builtin_bit_cast(float, v[2] & 0xFFFF0000u);
        s6 += __builtin_bit_cast(float, v[3] << 16);
        s7 += __builtin_bit_cast(float, v[3] & 0xFFFF0000u);
    }
    __shared__ float red[8][256];
    red[rg][cg * 8 + 0] = s0; red[rg][cg * 8 + 1] = s1;
    red[rg][cg * 8 + 2] = s2; red[rg][cg * 8 + 3] = s3;
    red[rg][cg * 8 + 4] = s4; red[rg][cg * 8 + 5] = s5;
    red[rg][cg * 8 + 6] = s6; red[rg][cg * 8 + 7] = s7;
    __syncthreads();
    float t = 0.f;
#pragma unroll
    for (int q = 0; q < 8; ++q) t += red[q][threadIdx.x];
    atomicAdd(&pool[(size_t)g * POOL_W + layer * 256 + threadIdx.x], t);
}

// ---------------------------------------------------------------------------
// fc_head v3 (R13 win): two graphs per block — each L1w fragment loaded once
// and dotted against both p-vectors. Grid (32, 12).
// ---------------------------------------------------------------------------
__global__ __launch_bounds__(256) void fc_head(
    const float* __restrict__ pool, const int* __restrict__ start,
    const float* __restrict__ L1w, const float* __restrict__ L1b,
    const float* __restrict__ L2w, float* __restrict__ gsum)
{
    const int g0 = blockIdx.x * 2, g1 = g0 + 1;
    __shared__ float p[2][POOL_W];

    const float rc0 = 1.0f / fmaxf((float)(start[g0 + 1] - start[g0]), 1.0f);
    const float rc1 = 1.0f / fmaxf((float)(start[g1 + 1] - start[g1]), 1.0f);
    for (int i = threadIdx.x; i < POOL_W; i += 256) {
        p[0][i] = pool[(size_t)g0 * POOL_W + i] * rc0;
        p[1][i] = pool[(size_t)g1 * POOL_W + i] * rc1;
    }
    __syncthreads();

    const int wv = threadIdx.x >> 6, lane = threadIdx.x & 63;
    const float4* pA = (const float4*)p[0];
    const float4* pB = (const float4*)p[1];
    const float4 a0 = pA[lane], a1 = pA[lane + 64], a2 = pA[lane + 128];
    const float4 b0 = pB[lane], b1 = pB[lane + 64], b2 = pB[lane + 128];

    const int ob = blockIdx.y * 64 + wv * 16;
    float part0 = 0.0f, part1 = 0.0f;
#pragma unroll 4
    for (int t = 0; t < 16; ++t) {
        const int o = ob + t;
        const float4* wr = (const float4*)(L1w + (size_t)o * POOL_W);
        const float4 wa = wr[lane], wb = wr[lane + 64], wc = wr[lane + 128];
        float accA = wa.x * a0.x + wa.y * a0.y + wa.z * a0.z + wa.w * a0.w
                   + wb.x * a1.x + wb.y * a1.y + wb.z * a1.z + wb.w * a1.w
                   + wc.x * a2.x + wc.y * a2.y + wc.z * a2.z + wc.w * a2.w;
        float accB = wa.x * b0.x + wa.y * b0.y + wa.z * b0.z + wa.w * b0.w
                   + wb.x * b1.x + wb.y * b1.y + wb.z * b1.z + wb.w * b1.w
                   + wc.x * b2.x + wc.y * b2.y + wc.z * b2.z + wc.w * b2.w;
#pragma unroll
        for (int off = 32; off > 0; off >>= 1) {
            accA += __shfl_xor(accA, off);
            accB += __shfl_xor(accB, off);
        }
        if (lane == 0) {
            const float r = fmaxf(accA + L1b[o], 0.0f);
            const float s = fmaxf(accB + L1b[o], 0.0f);
            part0 += r * L2w[o];
            part1 += s * L2w[o];
        }
    }
    if (lane == 0) {
        atomicAdd(&gsum[g0], part0);
        atomicAdd(&gsum[g1], part1);
    }
}

__global__ __launch_bounds__(64) void sig_kernel(
    const float* __restrict__ gsum, const float* __restrict__ L2b,
    float* __restrict__ out)
{
    const int g = threadIdx.x;
    if (g < N_GRAPHS) out[g] = 1.0f / (1.0f + expf(-(gsum[g] + L2b[0])));
}

// ---------------------------------------------------------------------------
extern "C" void kernel_launch(void* const* d_in, const int* in_sizes, int n_in,
                              void* d_out, int out_size, void* d_ws, size_t ws_size,
                              hipStream_t stream)
{
    const float* x     = (const float*)d_in[0];
    const float* ea    = (const float*)d_in[1];
    const int*   src   = (const int*)d_in[2];
    const int*   dst   = (const int*)d_in[3];
    const int*   batch = (const int*)d_in[4];

    const float* We[3]; const float* be[3]; const float* Wa[3]; const float* ba[3];
    const float* gg[3]; const float* bt[3]; const float* Wb[3]; const float* bb[3];
    for (int l = 0; l < 3; ++l) {
        const int o = 5 + 8 * l;
        We[l] = (const float*)d_in[o + 0]; be[l] = (const float*)d_in[o + 1];
        Wa[l] = (const float*)d_in[o + 2]; ba[l] = (const float*)d_in[o + 3];
        gg[l] = (const float*)d_in[o + 4]; bt[l] = (const float*)d_in[o + 5];
        Wb[l] = (const float*)d_in[o + 6]; bb[l] = (const float*)d_in[o + 7];
    }
    const float* L1w = (const float*)d_in[29];
    const float* L1b = (const float*)d_in[30];
    const float* L2w = (const float*)d_in[31];
    const float* L2b = (const float*)d_in[32];

    // ---- workspace layout ----
    float* pool   = (float*)d_ws;                              // 64*768
    float* gsum   = pool + (size_t)N_GRAPHS * POOL_W;          // 64 (zeroed with pool)
    int*   deg    = (int*)(gsum + N_GRAPHS);                   // N
    int*   off    = deg + N_NODES;                             // N+1
    int*   cursor = off + N_NODES + 1;                         // N
    int*   start  = cursor + N_NODES;                          // 72
    int*   cmap   = start + 72;                                // NCHUNK+1
    int*   ssrc   = (int*)((((uintptr_t)(cmap + NCHUNK + 1)) + 31) & ~(uintptr_t)31);  // E+16 ints, CSR
    unsigned short* eas = (unsigned short*)((((uintptr_t)(ssrc + N_EDGES + 16)) + 31) & ~(uintptr_t)31); // [E+16,16] f16 CSR
    unsigned short* xb = (unsigned short*)((((uintptr_t)(eas + (size_t)(N_EDGES + 16) * 16)) + 31) & ~(uintptr_t)31);
    unsigned short* u  = xb + (size_t)M_PAD * DIN;             // [M_PAD,256] (layer1 uses 128)
    unsigned short* h1 = u  + (size_t)M_PAD * H;
    unsigned short* h2 = h1 + (size_t)M_PAD * H;
    unsigned short* h3 = h2 + (size_t)M_PAD * H;
    unsigned short* wbf[6];
    wbf[0] = h3 + (size_t)M_PAD * H;                           // Wa1 frag [256,128]
    wbf[1] = wbf[0] + H * DIN;
    for (int i = 2; i < 6; ++i) wbf[i] = wbf[i - 1] + H * H;
    unsigned short* weh[3];
    weh[0] = wbf[5] + H * H;                                   // We1 [128,16] f16
    weh[1] = weh[0] + DIN * 16;                                // We2 [256,16] f16
    weh[2] = weh[1] + H * 16;                                  // We3 [256,16] f16

    // batched converts + deg/pool+gsum zeroing in one launch (12 jobs)
    CvtJobs jobs;
    jobs.j[0]  = { x,       xb,                    N_NODES * DIN / 4,       0, 0 };
    jobs.j[1]  = { Wa[0],   wbf[0],                H * DIN / 8,             3, DIN };
    jobs.j[2]  = { Wb[0],   wbf[1],                H * H / 8,               3, H };
    jobs.j[3]  = { Wa[1],   wbf[2],                H * H / 8,               3, H };
    jobs.j[4]  = { Wb[1],   wbf[3],                H * H / 8,               3, H };
    jobs.j[5]  = { Wa[2],   wbf[4],                H * H / 8,               3, H };
    jobs.j[6]  = { Wb[2],   wbf[5],                H * H / 8,               3, H };
    jobs.j[7]  = { nullptr, (unsigned short*)deg,  N_NODES * 4 / 8,         2, 0 };  // zero N ints
    jobs.j[8]  = { nullptr, (unsigned short*)pool, (N_GRAPHS * POOL_W + N_GRAPHS) * 4 / 8, 2, 0 }; // zero pool+gsum
    jobs.j[9]  = { We[0],   weh[0],                DIN * 16 / 4,            1, 0 };
    jobs.j[10] = { We[1],   weh[1],                H * 16 / 4,              1, 0 };
    jobs.j[11] = { We[2],   weh[2],                H * 16 / 4,              1, 0 };
    cvt_all<<<dim3(320, 12), 256, 0, stream>>>(jobs);

    // CSR + graph boundaries; scatter also computes chunk map + ssrc pad
    hist_kernel<<<EDGE_BLOCKS, 256, 0, stream>>>(dst, deg);
    scan_kernel<<<1, 1024, 0, stream>>>(deg, off, cursor, batch, start);
    scatter_kernel<<<EDGE_BLOCKS + CMAP_BLOCKS, 256, 0, stream>>>(
        src, dst, ea, cursor, ssrc, eas, off, cmap);

    const int agrid = NCHUNK / 4;               // agg3: 1 chunk/wave, 4 waves/block
    const int ggrid = M_PAD / 64;               // gemm_fused: 313 blocks x 512

    // ---- layer 1 (in=128) ----
    agg3<DIN><<<agrid, 256, 0, stream>>>(xb, eas, ssrc, off, cmap, weh[0], be[0], u);
    gemm_fused<DIN><<<ggrid, 512, 0, stream>>>(u, wbf[0], ba[0], gg[0], bt[0], wbf[1], bb[0], h1);
    // ---- layer 2 ----
    agg3<H><<<agrid, 256, 0, stream>>>(h1, eas, ssrc, off, cmap, weh[1], be[1], u);
    gemm_fused<H><<<ggrid, 512, 0, stream>>>(u, wbf[2], ba[1], gg[1], bt[1], wbf[3], bb[1], h2);
    // ---- layer 3 ----
    agg3<H><<<agrid, 256, 0, stream>>>(h2, eas, ssrc, off, cmap, weh[2], be[2], u);
    gemm_fused<H><<<ggrid, 512, 0, stream>>>(u, wbf[4], ba[2], gg[2], bt[2], wbf[5], bb[2], h3);

    // parallel mean-pool + head (fc_head: 2 graphs/block)
    pool2<<<dim3(3 * N_GRAPHS, RSPLIT), 256, 0, stream>>>(h1, h2, h3, start, pool);
    fc_head<<<dim3(N_GRAPHS / 2, POOL_W / 64), 256, 0, stream>>>(pool, start, L1w, L1b, L2w, gsum);
    sig_kernel<<<1, 64, 0, stream>>>(gsum, L2b, (float*)d_out);
}

// Round 18
// 437.509 us; speedup vs baseline: 1.1774x; 1.0090x over previous
//
#include <hip/hip_runtime.h>
#include <math.h>
#include <stdint.h>

#define N_NODES 20000
#define M_PAD 20032            // 313 * 64
#define N_EDGES 320000
#define N_GRAPHS 64
#define DIN 128
#define H 256
#define POOL_W 768
#define CHUNK 40               // edges per wave in agg3
#define NCHUNK (N_EDGES / CHUNK)   // 8000 (exact)
#define EDGE_BLOCKS ((N_EDGES + 255) / 256)    // 1250
#define CMAP_BLOCKS ((NCHUNK + 1 + 255) / 256) // 32

typedef __attribute__((ext_vector_type(8))) short bf16x8;   // 8 bf16 = 4 VGPRs
typedef __attribute__((ext_vector_type(4))) float f32x4;
typedef __attribute__((ext_vector_type(4))) unsigned int u32x4;
typedef __attribute__((ext_vector_type(2))) unsigned int u32x2;
typedef _Float16 h2 __attribute__((ext_vector_type(2)));    // packed f16 pair (1 VGPR)

__device__ __forceinline__ unsigned short f2bf(float f) {
    unsigned u = __builtin_bit_cast(unsigned, f);
    u += 0x7FFFu + ((u >> 16) & 1u);          // round-to-nearest-even
    return (unsigned short)(u >> 16);
}
__device__ __forceinline__ float bf2f(unsigned short u) {
    return __builtin_bit_cast(float, (unsigned)u << 16);
}
__device__ __forceinline__ unsigned short f2h(float f) {
    const _Float16 h = (_Float16)f;
    return __builtin_bit_cast(unsigned short, h);
}

#if __has_builtin(__builtin_amdgcn_fdot2)
#define DOT2(a, b, c) __builtin_amdgcn_fdot2((a), (b), (c), false)
#else
__device__ __forceinline__ float dot2_fallback(h2 a, h2 b, float c) {
    return fmaf((float)a.x, (float)b.x, fmaf((float)a.y, (float)b.y, c));
}
#define DOT2(a, b, c) dot2_fallback((a), (b), (c))
#endif

// ---------------------------------------------------------------------------
// Batched converts + zero jobs: 12 jobs, one launch.
// mode 0: fp32 -> bf16 row-major     mode 1: fp32 -> f16
// mode 2: zero fill                  mode 3: fp32 W[256][K] -> MFMA-fragment
// ---------------------------------------------------------------------------
struct CvtJob  { const float* s; unsigned short* d; int n4; int mode; int kdim; };
struct CvtJobs { CvtJob j[12]; };

__global__ __launch_bounds__(256) void cvt_all(CvtJobs jobs)
{
    const CvtJob J = jobs.j[blockIdx.y];
    if (J.mode == 2) {
        const ushort4 z = {0, 0, 0, 0};
        for (int i = blockIdx.x * 256 + threadIdx.x; i < J.n4; i += gridDim.x * 256)
            ((ushort4*)J.d)[i] = z;
        return;
    }
    if (J.mode == 1) {
        for (int i = blockIdx.x * 256 + threadIdx.x; i < J.n4; i += gridDim.x * 256) {
            const float4 v = ((const float4*)J.s)[i];
            ushort4 r;
            r.x = f2h(v.x); r.y = f2h(v.y); r.z = f2h(v.z); r.w = f2h(v.w);
            ((ushort4*)J.d)[i] = r;
        }
        return;
    }
    if (J.mode == 3) {
        const int K = J.kdim, KC = K / 32;
        for (int t = blockIdx.x * 256 + threadIdx.x; t < J.n4; t += gridDim.x * 256) {
            int unit = t;
            const int lane = unit & 63; unit >>= 6;
            const int half = unit & 1;  unit >>= 1;
            const int c = unit % KC;
            const int g = unit / KC;
            const int row = g * 32 + half * 16 + (lane & 15);
            const int kb  = c * 32 + ((lane >> 4) << 3);
            const float4 v0 = *(const float4*)(J.s + (size_t)row * K + kb);
            const float4 v1 = *(const float4*)(J.s + (size_t)row * K + kb + 4);
            ushort4 r0, r1;
            r0.x = f2bf(v0.x); r0.y = f2bf(v0.y); r0.z = f2bf(v0.z); r0.w = f2bf(v0.w);
            r1.x = f2bf(v1.x); r1.y = f2bf(v1.y); r1.z = f2bf(v1.z); r1.w = f2bf(v1.w);
            ushort4* dst = (ushort4*)(J.d + (size_t)t * 8);
            dst[0] = r0; dst[1] = r1;
        }
        return;
    }
    for (int i = blockIdx.x * 256 + threadIdx.x; i < J.n4; i += gridDim.x * 256) {
        const float4 v = ((const float4*)J.s)[i];
        ushort4 r;
        r.x = f2bf(v.x); r.y = f2bf(v.y); r.z = f2bf(v.z); r.w = f2bf(v.w);
        ((ushort4*)J.d)[i] = r;
    }
}

// ---------------------------------------------------------------------------
// CSR build
// ---------------------------------------------------------------------------
__global__ __launch_bounds__(256) void hist_kernel(const int* __restrict__ dst,
                                                   int* __restrict__ deg)
{
    const int i = blockIdx.x * 256 + threadIdx.x;
    if (i < N_EDGES) atomicAdd(deg + dst[i], 1);
}

// shfl scan; writes off and cursor; tail threads also compute graph starts.
__global__ __launch_bounds__(1024) void scan_kernel(const int* __restrict__ deg,
                                                    int* __restrict__ off,
                                                    int* __restrict__ cur,
                                                    const int* __restrict__ batch,
                                                    int* __restrict__ start)
{
    __shared__ int wsum[16];
    __shared__ int carry;
    const int tid = threadIdx.x, wave = tid >> 6, lane = tid & 63;
    if (tid == 0) carry = 0;
    __syncthreads();
    for (int base = 0; base < N_NODES; base += 1024) {
        const int i = base + tid;
        const int v = (i < N_NODES) ? deg[i] : 0;
        int s = v;
#pragma unroll
        for (int d = 1; d < 64; d <<= 1) {
            const int t = __shfl_up(s, d);
            if (lane >= d) s += t;
        }
        if (lane == 63) wsum[wave] = s;
        __syncthreads();
        if (wave == 0) {
            int t = (lane < 16) ? wsum[lane] : 0;
#pragma unroll
            for (int d = 1; d < 16; d <<= 1) {
                const int u = __shfl_up(t, d);
                if (lane >= d) t += u;
            }
            if (lane < 16) wsum[lane] = t;
        }
        __syncthreads();
        const int wbase = (wave == 0) ? 0 : wsum[wave - 1];
        if (i < N_NODES) {
            const int o = carry + wbase + s - v;
            off[i] = o;
            cur[i] = o;
        }
        const int tot = wsum[15];
        __syncthreads();
        if (tid == 0) carry += tot;
        __syncthreads();
    }
    if (tid == 0) off[N_NODES] = carry;

    // graph boundaries (batch is sorted)
    if (tid <= N_GRAPHS) {
        if (tid == N_GRAPHS) { start[N_GRAPHS] = N_NODES; }
        else {
            int lo = 0, hi = N_NODES;
            while (lo < hi) { const int mid = (lo + hi) >> 1; if (batch[mid] < tid) lo = mid + 1; else hi = mid; }
            start[tid] = lo;
        }
    }
}

// scatter v4: edge blocks build CSR-sorted (src, ea_f16); trailing 32 blocks
// compute the chunk->node map (block-parallel — R9 lesson) AND zero the
// 16-entry ssrc pad (pad entries are loaded by agg3's pipeline and
// dereferenced as node ids — must be valid; node 0 is always valid).
__global__ __launch_bounds__(256) void scatter_kernel(
    const int* __restrict__ src, const int* __restrict__ dst,
    const float* __restrict__ ea, int* __restrict__ cursor,
    int* __restrict__ ssrc, unsigned short* __restrict__ eas,
    const int* __restrict__ off, int* __restrict__ cmap)
{
    if (blockIdx.x >= EDGE_BLOCKS) {         // chunkmap + pad part
        const int w = (blockIdx.x - EDGE_BLOCKS) * 256 + threadIdx.x;
        if (w < 16) ssrc[N_EDGES + w] = 0;   // init pad (valid node id)
        if (w > NCHUNK) return;
        if (w == NCHUNK) { cmap[w] = N_NODES; return; }
        const int target = w * CHUNK;
        int lo = 0, hi = N_NODES;            // first n with off[n] >= target
        while (lo < hi) { const int mid = (lo + hi) >> 1; if (off[mid] < target) lo = mid + 1; else hi = mid; }
        cmap[w] = lo;
        return;
    }
    const int e = blockIdx.x * 256 + threadIdx.x;
    if (e < N_EDGES) {
        const int p = atomicAdd(cursor + dst[e], 1);
        ssrc[p] = src[e];
        const float4* er = (const float4*)(ea + (size_t)e * 16);
        ushort4* d4 = (ushort4*)(eas + (size_t)p * 16);
#pragma unroll
        for (int q = 0; q < 4; ++q) {
            const float4 v = er[q];
            ushort4 r;
            r.x = f2h(v.x); r.y = f2h(v.y); r.z = f2h(v.z); r.w = f2h(v.w);
            d4[q] = r;
        }
    }
}

// ---------------------------------------------------------------------------
// agg3 v10 — DEPTH-6 pipeline probe. R17 evidence: strength-reducing the
// address math cut VALUBusy 49->42% with ZERO time change -> agg3 is
// latency-exposed, not issue-bound. Depth 4->6 grows per-wave loads in
// flight +50% and the src->x chain slack 4->6 edges. Skeleton, flush,
// incrementing pointers, launch bounds (256,4) unchanged. Pad safety: max
// prefetch p+12 <= E+11 < E+16. Failure signature: VGPR>64 or WRITE jump
// = spill -> revert to R16 depth-4.
// out[v] = bf16( x[v] + sum_e relu(x[src] + ea@We.T + be) )
// ---------------------------------------------------------------------------
template<int IN>
__global__ __launch_bounds__(256, 4) void agg3(
    const unsigned short* __restrict__ xb,   // [M_PAD, IN] bf16
    const unsigned short* __restrict__ eas,  // [E+16,16] f16, CSR order
    const int* __restrict__ ssrc,            // [E+16] src, CSR order (pad=0)
    const int* __restrict__ off,             // [N+1]
    const int* __restrict__ cmap,            // [NCHUNK+1]
    const unsigned short* __restrict__ Weh,  // [IN,16] f16
    const float* __restrict__ be,
    unsigned short* __restrict__ out)        // [M_PAD, IN] bf16
{
    constexpr int CPL = IN / 64;             // 2 (layer1) or 4
    constexpr int XW  = CPL / 2;             // x-row dwords per lane: 1 or 2
    const int lane = threadIdx.x & 63;
    const int wid  = blockIdx.x * 4 + (threadIdx.x >> 6);
    const int c0 = lane * CPL;
    const int zd = __builtin_amdgcn_mbcnt_lo(0u, 0u);   // divergent zero: defeats SMEM scalarization

    // weights: CPL rows x 16 f16 — loaded once, best-effort pinned
    u32x4 wlo[CPL], whi[CPL];
    float bias[CPL], acc[CPL];
#pragma unroll
    for (int j = 0; j < CPL; ++j) {
        const u32x4* wr = (const u32x4*)(Weh + (size_t)(c0 + j) * 16);
        wlo[j] = wr[0];
        whi[j] = wr[1];
        bias[j] = be[c0 + j];
        acc[j]  = 0.0f;
    }
#pragma unroll
    for (int j = 0; j < CPL; ++j) {
#pragma unroll
        for (int k = 0; k < 4; ++k) {
            { float t = __builtin_bit_cast(float, wlo[j][k]); asm volatile("" : "+v"(t)); wlo[j][k] = __builtin_bit_cast(unsigned int, t); }
            { float t = __builtin_bit_cast(float, whi[j][k]); asm volatile("" : "+v"(t)); whi[j][k] = __builtin_bit_cast(unsigned int, t); }
        }
        asm volatile("" : "+v"(bias[j]));
    }

    int n          = __builtin_amdgcn_readfirstlane(cmap[wid]);
    const int nend = __builtin_amdgcn_readfirstlane(cmap[wid + 1]);
    if (n >= nend) return;                    // giant node spans this chunk
    int p          = __builtin_amdgcn_readfirstlane(off[n]);
    const int pend = __builtin_amdgcn_readfirstlane(off[nend]);

    auto ldx = [&](int s) -> u32x2 {          // row of xb (src gather or self)
        if constexpr (XW == 2) {
            return *(const u32x2*)(xb + (size_t)s * IN + c0);
        } else {
            u32x2 r;
            r[0] = *(const unsigned int*)(xb + (size_t)s * IN + c0);
            r[1] = 0u;
            return r;
        }
    };
    auto flushv = [&](int nn, u32x2 xs) {     // store bf16(x[nn] + acc); acc = 0
        if constexpr (XW == 2) {
            const float x0 = __builtin_bit_cast(float, xs[0] << 16);
            const float x1 = __builtin_bit_cast(float, xs[0] & 0xFFFF0000u);
            const float x2 = __builtin_bit_cast(float, xs[1] << 16);
            const float x3 = __builtin_bit_cast(float, xs[1] & 0xFFFF0000u);
            u32x2 o;
            o[0] = (unsigned)f2bf(x0 + acc[0]) | ((unsigned)f2bf(x1 + acc[1]) << 16);
            o[1] = (unsigned)f2bf(x2 + acc[2]) | ((unsigned)f2bf(x3 + acc[3]) << 16);
            *(u32x2*)(out + (size_t)nn * IN + c0) = o;
        } else {
            const float x0 = __builtin_bit_cast(float, xs[0] << 16);
            const float x1 = __builtin_bit_cast(float, xs[0] & 0xFFFF0000u);
            const unsigned int o =
                (unsigned)f2bf(x0 + acc[0]) | ((unsigned)f2bf(x1 + acc[1]) << 16);
            *(unsigned int*)(out + (size_t)nn * IN + c0) = o;
        }
#pragma unroll
        for (int j = 0; j < CPL; ++j) acc[j] = 0.0f;
    };

    // zero-degree nodes at the head of the range (immediate x loads — rare)
    int p1 = __builtin_amdgcn_readfirstlane(off[n + 1]);
    while (p1 == p) {
        flushv(n, ldx(n)); ++n;
        if (n >= nend) return;
        p1 = __builtin_amdgcn_readfirstlane(off[n + 1]);
    }
    // here: current node n non-empty, p = off[n] < p1 <= pend
    u32x2 xself = ldx(n);                     // prefetched; consumed at flush

    auto edge_compute = [&](u32x4 eL, u32x4 eH, u32x2 xw) {
        float m[CPL];
#pragma unroll
        for (int j = 0; j < CPL; ++j) m[j] = bias[j];
#pragma unroll
        for (int k = 0; k < 4; ++k) {
            const h2 ep = __builtin_bit_cast(h2, eL[k]);
#pragma unroll
            for (int j = 0; j < CPL; ++j)
                m[j] = DOT2(ep, __builtin_bit_cast(h2, wlo[j][k]), m[j]);
        }
#pragma unroll
        for (int k = 0; k < 4; ++k) {
            const h2 ep = __builtin_bit_cast(h2, eH[k]);
#pragma unroll
            for (int j = 0; j < CPL; ++j)
                m[j] = DOT2(ep, __builtin_bit_cast(h2, whi[j][k]), m[j]);
        }
#pragma unroll
        for (int j = 0; j < CPL; ++j) {
            const unsigned int word = xw[j >> 1];
            const float xf = __builtin_bit_cast(float,
                (j & 1) ? (word & 0xFFFF0000u) : (word << 16));
            acc[j] += fmaxf(m[j] + xf, 0.0f);
        }
    };
    // flush current node (prefetched xself) + zero-degree ties; prefetch next
    auto adv = [&]() {
        flushv(n, xself); ++n;
        while (n < nend) {
            p1 = __builtin_amdgcn_readfirstlane(off[n + 1]);
            if (p1 != p) { xself = ldx(n); break; }
            flushv(n, ldx(n)); ++n;           // zero-degree tie: immediate (rare)
        }
    };

    // incrementing divergent edge-stream pointers (zd folded into base once)
    const u32x4* pe = (const u32x4*)eas + ((size_t)(p + zd)) * 2;  // 2 u32x4/row
    const int*   ps = ssrc + p + zd;

    // depth-6 pipeline, in-place buffers, runs across node boundaries
    int sA = ps[0], sB = ps[1], sC = ps[2], sD = ps[3], sE = ps[4], sF = ps[5];
    u32x4 eLA = pe[0],  eHA = pe[1];
    u32x4 eLB = pe[2],  eHB = pe[3];
    u32x4 eLC = pe[4],  eHC = pe[5];
    u32x4 eLD = pe[6],  eHD = pe[7];
    u32x4 eLE = pe[8],  eHE = pe[9];
    u32x4 eLF = pe[10], eHF = pe[11];
    u32x2 xA = ldx(sA), xB = ldx(sB), xC = ldx(sC);
    u32x2 xD = ldx(sD), xE = ldx(sE), xF = ldx(sF);
    sA = ps[6]; sB = ps[7]; sC = ps[8]; sD = ps[9]; sE = ps[10]; sF = ps[11];

    for (;;) {
        edge_compute(eLA, eHA, xA);
        eLA = pe[12]; eHA = pe[13]; xA = ldx(sA); sA = ps[12];
        pe += 2; ++ps;
        ++p; if (p == p1) adv();
        if (p >= pend) break;

        edge_compute(eLB, eHB, xB);
        eLB = pe[12]; eHB = pe[13]; xB = ldx(sB); sB = ps[12];
        pe += 2; ++ps;
        ++p; if (p == p1) adv();
        if (p >= pend) break;

        edge_compute(eLC, eHC, xC);
        eLC = pe[12]; eHC = pe[13]; xC = ldx(sC); sC = ps[12];
        pe += 2; ++ps;
        ++p; if (p == p1) adv();
        if (p >= pend) break;

        edge_compute(eLD, eHD, xD);
        eLD = pe[12]; eHD = pe[13]; xD = ldx(sD); sD = ps[12];
        pe += 2; ++ps;
        ++p; if (p == p1) adv();
        if (p >= pend) break;

        edge_compute(eLE, eHE, xE);
        eLE = pe[12]; eHE = pe[13]; xE = ldx(sE); sE = ps[12];
        pe += 2; ++ps;
        ++p; if (p == p1) adv();
        if (p >= pend) break;

        edge_compute(eLF, eHF, xF);
        eLF = pe[12]; eHF = pe[13]; xF = ldx(sF); sF = ps[12];
        pe += 2; ++ps;
        ++p; if (p == p1) adv();
        if (p >= pend) break;
    }
    // safety: trailing zero-degree nodes (normally handled by adv)
    while (n < nend) { flushv(n, ldx(n)); ++n; }
}

// ---------------------------------------------------------------------------
// gemm_fused v3 (kept from R12, −17 us: frag-packed B). Both GEMMs of a GINE
// layer in one 512-thread kernel: LDS A-tile (XOR 16B-slot swizzle), stage1
// MFMA (Wa frags coalesced) -> BN+relu -> swizzled t tile in LDS, barrier,
// stage2 MFMA (Wb frags) -> bias+relu -> h.
// ---------------------------------------------------------------------------
template<int K>
__global__ __launch_bounds__(512, 4) void gemm_fused(
    const unsigned short* __restrict__ A,    // [M_PAD, K] (u)
    const unsigned short* __restrict__ WaF,  // frag-packed Wa (g,c,half,lane)
    const float* __restrict__ ba,
    const float* __restrict__ gsc, const float* __restrict__ bsh,
    const unsigned short* __restrict__ WbF,  // frag-packed Wb
    const float* __restrict__ bb,
    unsigned short* __restrict__ out)        // [M_PAD, 256] (h)
{
    constexpr int KC1 = K / 32;              // stage1 k-chunks: 4 or 8
    constexpr int KC2 = H / 32;              // stage2 k-chunks: 8
    constexpr int SLOTS = K / 8;             // 16B slots per A row
    __shared__ unsigned short Al[64 * K];    // 16/32 KB
    __shared__ unsigned short Tl[64 * H];    // 32 KB, swizzled slots

    const int w = threadIdx.x >> 6, lane = threadIdx.x & 63;
    const int lm = lane & 15, lq = lane >> 4;
    const int n0 = w * 32;                   // this wave's 32 output cols
    const int m0 = blockIdx.x * 64;

    const bf16x8* Wa8 = (const bf16x8*)WaF;
    const bf16x8* Wb8 = (const bf16x8*)WbF;

    // cooperative A-tile stage (512 threads), XOR-swizzled 16B slots
#pragma unroll
    for (int i = 0; i < 64 * SLOTS / 512; ++i) {
        const int t = i * 512 + threadIdx.x;
        const int row = t / SLOTS, slot = t % SLOTS;
        const uint4 v = *(const uint4*)(A + (size_t)(m0 + row) * K + slot * 8);
        *(uint4*)((char*)Al + row * (K * 2) + ((slot ^ (row & 7)) * 16)) = v;
    }

    const float inv = rsqrtf(1.0f + 1e-5f);
    const float bc0 = ba[n0 + lm],  bc1 = ba[n0 + 16 + lm];
    const float gc0 = gsc[n0 + lm], gc1 = gsc[n0 + 16 + lm];
    const float sc0 = bsh[n0 + lm], sc1 = bsh[n0 + 16 + lm];

    __syncthreads();

    // ---- stage 1: t = relu((u@Wa^T + ba)*inv*g + bt) -> LDS (half-K passes)
    {
        f32x4 acc0[4], acc1[4];
#pragma unroll
        for (int ch = 0; ch < 4; ++ch) {
            acc0[ch] = (f32x4){0.f, 0.f, 0.f, 0.f};
            acc1[ch] = (f32x4){0.f, 0.f, 0.f, 0.f};
        }
#pragma unroll
        for (int kh = 0; kh < KC1; kh += 4) {
            bf16x8 C0[4], C1[4];
#pragma unroll
            for (int c = 0; c < 4; ++c) {
                const int fi = (w * KC1 + kh + c) * 2;
                C0[c] = Wa8[(size_t)(fi + 0) * 64 + lane];
                C1[c] = Wa8[(size_t)(fi + 1) * 64 + lane];
            }
#pragma unroll
            for (int ch = 0; ch < 4; ++ch) {
                const int row = ch * 16 + lm;
                const char* rbase = (const char*)Al + row * (K * 2);
#pragma unroll
                for (int c = 0; c < 4; ++c) {
                    const int slot = (lq + (kh + c) * 4) ^ (row & 7);
                    const bf16x8 a = *(const bf16x8*)(rbase + slot * 16);
                    acc0[ch] = __builtin_amdgcn_mfma_f32_16x16x32_bf16(a, C0[c], acc0[ch], 0, 0, 0);
                    acc1[ch] = __builtin_amdgcn_mfma_f32_16x16x32_bf16(a, C1[c], acc1[ch], 0, 0, 0);
                }
            }
        }
        // write t tile to LDS (bf16, swizzled slots)
#pragma unroll
        for (int ch = 0; ch < 4; ++ch) {
#pragma unroll
            for (int r = 0; r < 4; ++r) {
                const int rowo = ch * 16 + lq * 4 + r;
                const float v0 = fmaxf((acc0[ch][r] + bc0) * inv * gc0 + sc0, 0.0f);
                const float v1 = fmaxf((acc1[ch][r] + bc1) * inv * gc1 + sc1, 0.0f);
                const int col0 = n0 + lm, col1 = n0 + 16 + lm;
                *(unsigned short*)((char*)Tl + rowo * (H * 2)
                    + (((col0 >> 3) ^ (rowo & 7)) << 4) + ((col0 & 7) << 1)) = f2bf(v0);
                *(unsigned short*)((char*)Tl + rowo * (H * 2)
                    + (((col1 >> 3) ^ (rowo & 7)) << 4) + ((col1 & 7) << 1)) = f2bf(v1);
            }
        }
    }

    const float eb0 = bb[n0 + lm], eb1 = bb[n0 + 16 + lm];

    __syncthreads();

    // ---- stage 2: h = relu(t @ Wb^T + bb) (half-K passes)
    {
        f32x4 acc0[4], acc1[4];
#pragma unroll
        for (int ch = 0; ch < 4; ++ch) {
            acc0[ch] = (f32x4){0.f, 0.f, 0.f, 0.f};
            acc1[ch] = (f32x4){0.f, 0.f, 0.f, 0.f};
        }
#pragma unroll
        for (int kh = 0; kh < KC2; kh += 4) {
            bf16x8 C0[4], C1[4];
#pragma unroll
            for (int c = 0; c < 4; ++c) {
                const int fi = (w * KC2 + kh + c) * 2;
                C0[c] = Wb8[(size_t)(fi + 0) * 64 + lane];
                C1[c] = Wb8[(size_t)(fi + 1) * 64 + lane];
            }
#pragma unroll
            for (int ch = 0; ch < 4; ++ch) {
                const int row = ch * 16 + lm;
                const char* rbase = (const char*)Tl + row * (H * 2);
#pragma unroll
                for (int c = 0; c < 4; ++c) {
                    const int slot = (lq + (kh + c) * 4) ^ (row & 7);
                    const bf16x8 a = *(const bf16x8*)(rbase + slot * 16);
                    acc0[ch] = __builtin_amdgcn_mfma_f32_16x16x32_bf16(a, C0[c], acc0[ch], 0, 0, 0);
                    acc1[ch] = __builtin_amdgcn_mfma_f32_16x16x32_bf16(a, C1[c], acc1[ch], 0, 0, 0);
                }
            }
        }
#pragma unroll
        for (int ch = 0; ch < 4; ++ch) {
            const int mr = m0 + ch * 16;
#pragma unroll
            for (int r = 0; r < 4; ++r) {
                const int rowo = mr + lq * 4 + r;
                if (rowo >= N_NODES) continue;
                const float v0 = fmaxf(acc0[ch][r] + eb0, 0.0f);
                const float v1 = fmaxf(acc1[ch][r] + eb1, 0.0f);
                out[(size_t)rowo * H + n0 + lm]      = f2bf(v0);
                out[(size_t)rowo * H + n0 + 16 + lm] = f2bf(v1);
            }
        }
    }
}

// ---------------------------------------------------------------------------
// pool2 v2 (R13 win): u32x4 vectorized loads, 8 rows in flight, LDS
// cross-rowgroup reduce, one atomic per column.
// ---------------------------------------------------------------------------
#define RSPLIT 6
__global__ __launch_bounds__(256) void pool2(
    const unsigned short* __restrict__ h1, const unsigned short* __restrict__ h2,
    const unsigned short* __restrict__ h3, const int* __restrict__ start,
    float* __restrict__ pool)
{
    const int g = blockIdx.x & 63, layer = blockIdx.x >> 6;
    const unsigned short* h = (layer == 0) ? h1 : (layer == 1) ? h2 : h3;
    const int r0 = start[g], r1 = start[g + 1];
    const int nr = r1 - r0;
    if (nr <= 0) return;
    const int chunk = (nr + RSPLIT - 1) / RSPLIT;
    const int rs = r0 + blockIdx.y * chunk;
    const int re = (rs + chunk < r1) ? rs + chunk : r1;
    if (rs >= re) return;

    const int cg = threadIdx.x & 31;         // cols cg*8 .. cg*8+7
    const int rg = threadIdx.x >> 5;         // row group 0..7
    float s0 = 0.f, s1 = 0.f, s2 = 0.f, s3 = 0.f;
    float s4 = 0.f, s5 = 0.f, s6 = 0.f, s7 = 0.f;
    for (int r = rs + rg; r < re; r += 8) {
        const u32x4 v = *(const u32x4*)(h + (size_t)r * H + cg * 8);
        s0 += __builtin_bit_cast(float, v[0] << 16);
        s1 += __builtin_bit_cast(float, v[0] & 0xFFFF0000u);
        s2 += __builtin_bit_cast(float, v[1] << 16);
        s3 += __builtin_bit_cast(float, v[1] & 0xFFFF0000u);
        s4 += __builtin_bit_cast(float, v[2] << 16);
        s5 += __builtin_bit_cast(float, v[2] & 0xFFFF0000u);
        s6 += __builtin_bit_cast(float, v[3] << 16);
        s7 += __builtin_bit_cast(float, v[3] & 0xFFFF0000u);
    }
    __shared__ float red[8][256];
    red[rg][cg * 8 + 0] = s0; red[rg][cg * 8 + 1] = s1;
    red[rg][cg * 8 + 2] = s2; red[rg][cg * 8 + 3] = s3;
    red[rg][cg * 8 + 4] = s4; red[rg][cg * 8 + 5] = s5;
    red[rg][cg * 8 + 6] = s6; red[rg][cg * 8 + 7] = s7;
    __syncthreads();
    float t = 0.f;
#pragma unroll
    for (int q = 0; q < 8; ++q) t += red[q][threadIdx.x];
    atomicAdd(&pool[(size_t)g * POOL_W + layer * 256 + threadIdx.x], t);
}

// ---------------------------------------------------------------------------
// fc_head v3 (R13 win): two graphs per block — each L1w fragment loaded once
// and dotted against both p-vectors. Grid (32, 12).
// ---------------------------------------------------------------------------
__global__ __launch_bounds__(256) void fc_head(
    const float* __restrict__ pool, const int* __restrict__ start,
    const float* __restrict__ L1w, const float* __restrict__ L1b,
    const float* __restrict__ L2w, float* __restrict__ gsum)
{
    const int g0 = blockIdx.x * 2, g1 = g0 + 1;
    __shared__ float p[2][POOL_W];

    const float rc0 = 1.0f / fmaxf((float)(start[g0 + 1] - start[g0]), 1.0f);
    const float rc1 = 1.0f / fmaxf((float)(start[g1 + 1] - start[g1]), 1.0f);
    for (int i = threadIdx.x; i < POOL_W; i += 256) {
        p[0][i] = pool[(size_t)g0 * POOL_W + i] * rc0;
        p[1][i] = pool[(size_t)g1 * POOL_W + i] * rc1;
    }
    __syncthreads();

    const int wv = threadIdx.x >> 6, lane = threadIdx.x & 63;
    const float4* pA = (const float4*)p[0];
    const float4* pB = (const float4*)p[1];
    const float4 a0 = pA[lane], a1 = pA[lane + 64], a2 = pA[lane + 128];
    const float4 b0 = pB[lane], b1 = pB[lane + 64], b2 = pB[lane + 128];

    const int ob = blockIdx.y * 64 + wv * 16;
    float part0 = 0.0f, part1 = 0.0f;
#pragma unroll 4
    for (int t = 0; t < 16; ++t) {
        const int o = ob + t;
        const float4* wr = (const float4*)(L1w + (size_t)o * POOL_W);
        const float4 wa = wr[lane], wb = wr[lane + 64], wc = wr[lane + 128];
        float accA = wa.x * a0.x + wa.y * a0.y + wa.z * a0.z + wa.w * a0.w
                   + wb.x * a1.x + wb.y * a1.y + wb.z * a1.z + wb.w * a1.w
                   + wc.x * a2.x + wc.y * a2.y + wc.z * a2.z + wc.w * a2.w;
        float accB = wa.x * b0.x + wa.y * b0.y + wa.z * b0.z + wa.w * b0.w
                   + wb.x * b1.x + wb.y * b1.y + wb.z * b1.z + wb.w * b1.w
                   + wc.x * b2.x + wc.y * b2.y + wc.z * b2.z + wc.w * b2.w;
#pragma unroll
        for (int off = 32; off > 0; off >>= 1) {
            accA += __shfl_xor(accA, off);
            accB += __shfl_xor(accB, off);
        }
        if (lane == 0) {
            const float r = fmaxf(accA + L1b[o], 0.0f);
            const float s = fmaxf(accB + L1b[o], 0.0f);
            part0 += r * L2w[o];
            part1 += s * L2w[o];
        }
    }
    if (lane == 0) {
        atomicAdd(&gsum[g0], part0);
        atomicAdd(&gsum[g1], part1);
    }
}

__global__ __launch_bounds__(64) void sig_kernel(
    const float* __restrict__ gsum, const float* __restrict__ L2b,
    float* __restrict__ out)
{
    const int g = threadIdx.x;
    if (g < N_GRAPHS) out[g] = 1.0f / (1.0f + expf(-(gsum[g] + L2b[0])));
}

// ---------------------------------------------------------------------------
extern "C" void kernel_launch(void* const* d_in, const int* in_sizes, int n_in,
                              void* d_out, int out_size, void* d_ws, size_t ws_size,
                              hipStream_t stream)
{
    const float* x     = (const float*)d_in[0];
    const float* ea    = (const float*)d_in[1];
    const int*   src   = (const int*)d_in[2];
    const int*   dst   = (const int*)d_in[3];
    const int*   batch = (const int*)d_in[4];

    const float* We[3]; const float* be[3]; const float* Wa[3]; const float* ba[3];
    const float* gg[3]; const float* bt[3]; const float* Wb[3]; const float* bb[3];
    for (int l = 0; l < 3; ++l) {
        const int o = 5 + 8 * l;
        We[l] = (const float*)d_in[o + 0]; be[l] = (const float*)d_in[o + 1];
        Wa[l] = (const float*)d_in[o + 2]; ba[l] = (const float*)d_in[o + 3];
        gg[l] = (const float*)d_in[o + 4]; bt[l] = (const float*)d_in[o + 5];
        Wb[l] = (const float*)d_in[o + 6]; bb[l] = (const float*)d_in[o + 7];
    }
    const float* L1w = (const float*)d_in[29];
    const float* L1b = (const float*)d_in[30];
    const float* L2w = (const float*)d_in[31];
    const float* L2b = (const float*)d_in[32];

    // ---- workspace layout ----
    float* pool   = (float*)d_ws;                              // 64*768
    float* gsum   = pool + (size_t)N_GRAPHS * POOL_W;          // 64 (zeroed with pool)
    int*   deg    = (int*)(gsum + N_GRAPHS);                   // N
    int*   off    = deg + N_NODES;                             // N+1
    int*   cursor = off + N_NODES + 1;                         // N
    int*   start  = cursor + N_NODES;                          // 72
    int*   cmap   = start + 72;                                // NCHUNK+1
    int*   ssrc   = (int*)((((uintptr_t)(cmap + NCHUNK + 1)) + 31) & ~(uintptr_t)31);  // E+16 ints, CSR
    unsigned short* eas = (unsigned short*)((((uintptr_t)(ssrc + N_EDGES + 16)) + 31) & ~(uintptr_t)31); // [E+16,16] f16 CSR
    unsigned short* xb = (unsigned short*)((((uintptr_t)(eas + (size_t)(N_EDGES + 16) * 16)) + 31) & ~(uintptr_t)31);
    unsigned short* u  = xb + (size_t)M_PAD * DIN;             // [M_PAD,256] (layer1 uses 128)
    unsigned short* h1 = u  + (size_t)M_PAD * H;
    unsigned short* h2 = h1 + (size_t)M_PAD * H;
    unsigned short* h3 = h2 + (size_t)M_PAD * H;
    unsigned short* wbf[6];
    wbf[0] = h3 + (size_t)M_PAD * H;                           // Wa1 frag [256,128]
    wbf[1] = wbf[0] + H * DIN;
    for (int i = 2; i < 6; ++i) wbf[i] = wbf[i - 1] + H * H;
    unsigned short* weh[3];
    weh[0] = wbf[5] + H * H;                                   // We1 [128,16] f16
    weh[1] = weh[0] + DIN * 16;                                // We2 [256,16] f16
    weh[2] = weh[1] + H * 16;                                  // We3 [256,16] f16

    // batched converts + deg/pool+gsum zeroing in one launch (12 jobs)
    CvtJobs jobs;
    jobs.j[0]  = { x,       xb,                    N_NODES * DIN / 4,       0, 0 };
    jobs.j[1]  = { Wa[0],   wbf[0],                H * DIN / 8,             3, DIN };
    jobs.j[2]  = { Wb[0],   wbf[1],                H * H / 8,               3, H };
    jobs.j[3]  = { Wa[1],   wbf[2],                H * H / 8,               3, H };
    jobs.j[4]  = { Wb[1],   wbf[3],                H * H / 8,               3, H };
    jobs.j[5]  = { Wa[2],   wbf[4],                H * H / 8,               3, H };
    jobs.j[6]  = { Wb[2],   wbf[5],                H * H / 8,               3, H };
    jobs.j[7]  = { nullptr, (unsigned short*)deg,  N_NODES * 4 / 8,         2, 0 };  // zero N ints
    jobs.j[8]  = { nullptr, (unsigned short*)pool, (N_GRAPHS * POOL_W + N_GRAPHS) * 4 / 8, 2, 0 }; // zero pool+gsum
    jobs.j[9]  = { We[0],   weh[0],                DIN * 16 / 4,            1, 0 };
    jobs.j[10] = { We[1],   weh[1],                H * 16 / 4,              1, 0 };
    jobs.j[11] = { We[2],   weh[2],                H * 16 / 4,              1, 0 };
    cvt_all<<<dim3(320, 12), 256, 0, stream>>>(jobs);

    // CSR + graph boundaries; scatter also computes chunk map + ssrc pad
    hist_kernel<<<EDGE_BLOCKS, 256, 0, stream>>>(dst, deg);
    scan_kernel<<<1, 1024, 0, stream>>>(deg, off, cursor, batch, start);
    scatter_kernel<<<EDGE_BLOCKS + CMAP_BLOCKS, 256, 0, stream>>>(
        src, dst, ea, cursor, ssrc, eas, off, cmap);

    const int agrid = NCHUNK / 4;               // agg3: 1 chunk/wave, 4 waves/block
    const int ggrid = M_PAD / 64;               // gemm_fused: 313 blocks x 512

    // ---- layer 1 (in=128) ----
    agg3<DIN><<<agrid, 256, 0, stream>>>(xb, eas, ssrc, off, cmap, weh[0], be[0], u);
    gemm_fused<DIN><<<ggrid, 512, 0, stream>>>(u, wbf[0], ba[0], gg[0], bt[0], wbf[1], bb[0], h1);
    // ---- layer 2 ----
    agg3<H><<<agrid, 256, 0, stream>>>(h1, eas, ssrc, off, cmap, weh[1], be[1], u);
    gemm_fused<H><<<ggrid, 512, 0, stream>>>(u, wbf[2], ba[1], gg[1], bt[1], wbf[3], bb[1], h2);
    // ---- layer 3 ----
    agg3<H><<<agrid, 256, 0, stream>>>(h2, eas, ssrc, off, cmap, weh[2], be[2], u);
    gemm_fused<H><<<ggrid, 512, 0, stream>>>(u, wbf[4], ba[2], gg[2], bt[2], wbf[5], bb[2], h3);

    // parallel mean-pool + head (fc_head: 2 graphs/block)
    pool2<<<dim3(3 * N_GRAPHS, RSPLIT), 256, 0, stream>>>(h1, h2, h3, start, pool);
    fc_head<<<dim3(N_GRAPHS / 2, POOL_W / 64), 256, 0, stream>>>(pool, start, L1w, L1b, L2w, gsum);
    sig_kernel<<<1, 64, 0, stream>>>(gsum, L2b, (float*)d_out);
}

// Round 19
// 436.549 us; speedup vs baseline: 1.1800x; 1.0022x over previous
//
#include <hip/hip_runtime.h>
#include <math.h>
#include <stdint.h>

#define N_NODES 20000
#define M_PAD 20032            // 313 * 64 = 626 * 32
#define N_EDGES 320000
#define N_GRAPHS 64
#define DIN 128
#define H 256
#define POOL_W 768
#define CHUNK 40               // edges per wave in agg3
#define NCHUNK (N_EDGES / CHUNK)   // 8000 (exact)
#define EDGE_BLOCKS ((N_EDGES + 255) / 256)    // 1250
#define CMAP_BLOCKS ((NCHUNK + 1 + 255) / 256) // 32
#define BM 32                  // gemm M-tile (R19: 64->32 for 2x grid/occupancy)

typedef __attribute__((ext_vector_type(8))) short bf16x8;   // 8 bf16 = 4 VGPRs
typedef __attribute__((ext_vector_type(4))) float f32x4;
typedef __attribute__((ext_vector_type(4))) unsigned int u32x4;
typedef __attribute__((ext_vector_type(2))) unsigned int u32x2;
typedef _Float16 h2 __attribute__((ext_vector_type(2)));    // packed f16 pair (1 VGPR)

__device__ __forceinline__ unsigned short f2bf(float f) {
    unsigned u = __builtin_bit_cast(unsigned, f);
    u += 0x7FFFu + ((u >> 16) & 1u);          // round-to-nearest-even
    return (unsigned short)(u >> 16);
}
__device__ __forceinline__ float bf2f(unsigned short u) {
    return __builtin_bit_cast(float, (unsigned)u << 16);
}
__device__ __forceinline__ unsigned short f2h(float f) {
    const _Float16 h = (_Float16)f;
    return __builtin_bit_cast(unsigned short, h);
}

#if __has_builtin(__builtin_amdgcn_fdot2)
#define DOT2(a, b, c) __builtin_amdgcn_fdot2((a), (b), (c), false)
#else
__device__ __forceinline__ float dot2_fallback(h2 a, h2 b, float c) {
    return fmaf((float)a.x, (float)b.x, fmaf((float)a.y, (float)b.y, c));
}
#define DOT2(a, b, c) dot2_fallback((a), (b), (c))
#endif

// ---------------------------------------------------------------------------
// Batched converts + zero jobs: 12 jobs, one launch.
// mode 0: fp32 -> bf16 row-major     mode 1: fp32 -> f16
// mode 2: zero fill                  mode 3: fp32 W[256][K] -> MFMA-fragment
// ---------------------------------------------------------------------------
struct CvtJob  { const float* s; unsigned short* d; int n4; int mode; int kdim; };
struct CvtJobs { CvtJob j[12]; };

__global__ __launch_bounds__(256) void cvt_all(CvtJobs jobs)
{
    const CvtJob J = jobs.j[blockIdx.y];
    if (J.mode == 2) {
        const ushort4 z = {0, 0, 0, 0};
        for (int i = blockIdx.x * 256 + threadIdx.x; i < J.n4; i += gridDim.x * 256)
            ((ushort4*)J.d)[i] = z;
        return;
    }
    if (J.mode == 1) {
        for (int i = blockIdx.x * 256 + threadIdx.x; i < J.n4; i += gridDim.x * 256) {
            const float4 v = ((const float4*)J.s)[i];
            ushort4 r;
            r.x = f2h(v.x); r.y = f2h(v.y); r.z = f2h(v.z); r.w = f2h(v.w);
            ((ushort4*)J.d)[i] = r;
        }
        return;
    }
    if (J.mode == 3) {
        const int K = J.kdim, KC = K / 32;
        for (int t = blockIdx.x * 256 + threadIdx.x; t < J.n4; t += gridDim.x * 256) {
            int unit = t;
            const int lane = unit & 63; unit >>= 6;
            const int half = unit & 1;  unit >>= 1;
            const int c = unit % KC;
            const int g = unit / KC;
            const int row = g * 32 + half * 16 + (lane & 15);
            const int kb  = c * 32 + ((lane >> 4) << 3);
            const float4 v0 = *(const float4*)(J.s + (size_t)row * K + kb);
            const float4 v1 = *(const float4*)(J.s + (size_t)row * K + kb + 4);
            ushort4 r0, r1;
            r0.x = f2bf(v0.x); r0.y = f2bf(v0.y); r0.z = f2bf(v0.z); r0.w = f2bf(v0.w);
            r1.x = f2bf(v1.x); r1.y = f2bf(v1.y); r1.z = f2bf(v1.z); r1.w = f2bf(v1.w);
            ushort4* dst = (ushort4*)(J.d + (size_t)t * 8);
            dst[0] = r0; dst[1] = r1;
        }
        return;
    }
    for (int i = blockIdx.x * 256 + threadIdx.x; i < J.n4; i += gridDim.x * 256) {
        const float4 v = ((const float4*)J.s)[i];
        ushort4 r;
        r.x = f2bf(v.x); r.y = f2bf(v.y); r.z = f2bf(v.z); r.w = f2bf(v.w);
        ((ushort4*)J.d)[i] = r;
    }
}

// ---------------------------------------------------------------------------
// CSR build
// ---------------------------------------------------------------------------
__global__ __launch_bounds__(256) void hist_kernel(const int* __restrict__ dst,
                                                   int* __restrict__ deg)
{
    const int i = blockIdx.x * 256 + threadIdx.x;
    if (i < N_EDGES) atomicAdd(deg + dst[i], 1);
}

// shfl scan; writes off and cursor; tail threads also compute graph starts.
__global__ __launch_bounds__(1024) void scan_kernel(const int* __restrict__ deg,
                                                    int* __restrict__ off,
                                                    int* __restrict__ cur,
                                                    const int* __restrict__ batch,
                                                    int* __restrict__ start)
{
    __shared__ int wsum[16];
    __shared__ int carry;
    const int tid = threadIdx.x, wave = tid >> 6, lane = tid & 63;
    if (tid == 0) carry = 0;
    __syncthreads();
    for (int base = 0; base < N_NODES; base += 1024) {
        const int i = base + tid;
        const int v = (i < N_NODES) ? deg[i] : 0;
        int s = v;
#pragma unroll
        for (int d = 1; d < 64; d <<= 1) {
            const int t = __shfl_up(s, d);
            if (lane >= d) s += t;
        }
        if (lane == 63) wsum[wave] = s;
        __syncthreads();
        if (wave == 0) {
            int t = (lane < 16) ? wsum[lane] : 0;
#pragma unroll
            for (int d = 1; d < 16; d <<= 1) {
                const int u = __shfl_up(t, d);
                if (lane >= d) t += u;
            }
            if (lane < 16) wsum[lane] = t;
        }
        __syncthreads();
        const int wbase = (wave == 0) ? 0 : wsum[wave - 1];
        if (i < N_NODES) {
            const int o = carry + wbase + s - v;
            off[i] = o;
            cur[i] = o;
        }
        const int tot = wsum[15];
        __syncthreads();
        if (tid == 0) carry += tot;
        __syncthreads();
    }
    if (tid == 0) off[N_NODES] = carry;

    // graph boundaries (batch is sorted)
    if (tid <= N_GRAPHS) {
        if (tid == N_GRAPHS) { start[N_GRAPHS] = N_NODES; }
        else {
            int lo = 0, hi = N_NODES;
            while (lo < hi) { const int mid = (lo + hi) >> 1; if (batch[mid] < tid) lo = mid + 1; else hi = mid; }
            start[tid] = lo;
        }
    }
}

// scatter v4: edge blocks build CSR-sorted (src, ea_f16); trailing 32 blocks
// compute the chunk->node map (block-parallel — R9 lesson) AND zero the
// 16-entry ssrc pad (pad entries are loaded by agg3's pipeline and
// dereferenced as node ids — must be valid; node 0 is always valid).
__global__ __launch_bounds__(256) void scatter_kernel(
    const int* __restrict__ src, const int* __restrict__ dst,
    const float* __restrict__ ea, int* __restrict__ cursor,
    int* __restrict__ ssrc, unsigned short* __restrict__ eas,
    const int* __restrict__ off, int* __restrict__ cmap)
{
    if (blockIdx.x >= EDGE_BLOCKS) {         // chunkmap + pad part
        const int w = (blockIdx.x - EDGE_BLOCKS) * 256 + threadIdx.x;
        if (w < 16) ssrc[N_EDGES + w] = 0;   // init pad (valid node id)
        if (w > NCHUNK) return;
        if (w == NCHUNK) { cmap[w] = N_NODES; return; }
        const int target = w * CHUNK;
        int lo = 0, hi = N_NODES;            // first n with off[n] >= target
        while (lo < hi) { const int mid = (lo + hi) >> 1; if (off[mid] < target) lo = mid + 1; else hi = mid; }
        cmap[w] = lo;
        return;
    }
    const int e = blockIdx.x * 256 + threadIdx.x;
    if (e < N_EDGES) {
        const int p = atomicAdd(cursor + dst[e], 1);
        ssrc[p] = src[e];
        const float4* er = (const float4*)(ea + (size_t)e * 16);
        ushort4* d4 = (ushort4*)(eas + (size_t)p * 16);
#pragma unroll
        for (int q = 0; q < 4; ++q) {
            const float4 v = er[q];
            ushort4 r;
            r.x = f2h(v.x); r.y = f2h(v.y); r.z = f2h(v.z); r.w = f2h(v.w);
            d4[q] = r;
        }
    }
}

// ---------------------------------------------------------------------------
// agg3 v10 (R18 win: depth-6, 64 us, VGPR 56, no spill — PARKED).
// Edge-parallel segmented aggregation: 8000 waves x 40-edge CSR chunks,
// depth-6 in-place pipeline across node boundaries, wave-uniform SALU
// flush, xself prefetched, incrementing divergent pointers.
// out[v] = bf16( x[v] + sum_e relu(x[src] + ea@We.T + be) )
// ---------------------------------------------------------------------------
template<int IN>
__global__ __launch_bounds__(256, 4) void agg3(
    const unsigned short* __restrict__ xb,   // [M_PAD, IN] bf16
    const unsigned short* __restrict__ eas,  // [E+16,16] f16, CSR order
    const int* __restrict__ ssrc,            // [E+16] src, CSR order (pad=0)
    const int* __restrict__ off,             // [N+1]
    const int* __restrict__ cmap,            // [NCHUNK+1]
    const unsigned short* __restrict__ Weh,  // [IN,16] f16
    const float* __restrict__ be,
    unsigned short* __restrict__ out)        // [M_PAD, IN] bf16
{
    constexpr int CPL = IN / 64;             // 2 (layer1) or 4
    constexpr int XW  = CPL / 2;             // x-row dwords per lane: 1 or 2
    const int lane = threadIdx.x & 63;
    const int wid  = blockIdx.x * 4 + (threadIdx.x >> 6);
    const int c0 = lane * CPL;
    const int zd = __builtin_amdgcn_mbcnt_lo(0u, 0u);   // divergent zero: defeats SMEM scalarization

    // weights: CPL rows x 16 f16 — loaded once, best-effort pinned
    u32x4 wlo[CPL], whi[CPL];
    float bias[CPL], acc[CPL];
#pragma unroll
    for (int j = 0; j < CPL; ++j) {
        const u32x4* wr = (const u32x4*)(Weh + (size_t)(c0 + j) * 16);
        wlo[j] = wr[0];
        whi[j] = wr[1];
        bias[j] = be[c0 + j];
        acc[j]  = 0.0f;
    }
#pragma unroll
    for (int j = 0; j < CPL; ++j) {
#pragma unroll
        for (int k = 0; k < 4; ++k) {
            { float t = __builtin_bit_cast(float, wlo[j][k]); asm volatile("" : "+v"(t)); wlo[j][k] = __builtin_bit_cast(unsigned int, t); }
            { float t = __builtin_bit_cast(float, whi[j][k]); asm volatile("" : "+v"(t)); whi[j][k] = __builtin_bit_cast(unsigned int, t); }
        }
        asm volatile("" : "+v"(bias[j]));
    }

    int n          = __builtin_amdgcn_readfirstlane(cmap[wid]);
    const int nend = __builtin_amdgcn_readfirstlane(cmap[wid + 1]);
    if (n >= nend) return;                    // giant node spans this chunk
    int p          = __builtin_amdgcn_readfirstlane(off[n]);
    const int pend = __builtin_amdgcn_readfirstlane(off[nend]);

    auto ldx = [&](int s) -> u32x2 {          // row of xb (src gather or self)
        if constexpr (XW == 2) {
            return *(const u32x2*)(xb + (size_t)s * IN + c0);
        } else {
            u32x2 r;
            r[0] = *(const unsigned int*)(xb + (size_t)s * IN + c0);
            r[1] = 0u;
            return r;
        }
    };
    auto flushv = [&](int nn, u32x2 xs) {     // store bf16(x[nn] + acc); acc = 0
        if constexpr (XW == 2) {
            const float x0 = __builtin_bit_cast(float, xs[0] << 16);
            const float x1 = __builtin_bit_cast(float, xs[0] & 0xFFFF0000u);
            const float x2 = __builtin_bit_cast(float, xs[1] << 16);
            const float x3 = __builtin_bit_cast(float, xs[1] & 0xFFFF0000u);
            u32x2 o;
            o[0] = (unsigned)f2bf(x0 + acc[0]) | ((unsigned)f2bf(x1 + acc[1]) << 16);
            o[1] = (unsigned)f2bf(x2 + acc[2]) | ((unsigned)f2bf(x3 + acc[3]) << 16);
            *(u32x2*)(out + (size_t)nn * IN + c0) = o;
        } else {
            const float x0 = __builtin_bit_cast(float, xs[0] << 16);
            const float x1 = __builtin_bit_cast(float, xs[0] & 0xFFFF0000u);
            const unsigned int o =
                (unsigned)f2bf(x0 + acc[0]) | ((unsigned)f2bf(x1 + acc[1]) << 16);
            *(unsigned int*)(out + (size_t)nn * IN + c0) = o;
        }
#pragma unroll
        for (int j = 0; j < CPL; ++j) acc[j] = 0.0f;
    };

    // zero-degree nodes at the head of the range (immediate x loads — rare)
    int p1 = __builtin_amdgcn_readfirstlane(off[n + 1]);
    while (p1 == p) {
        flushv(n, ldx(n)); ++n;
        if (n >= nend) return;
        p1 = __builtin_amdgcn_readfirstlane(off[n + 1]);
    }
    // here: current node n non-empty, p = off[n] < p1 <= pend
    u32x2 xself = ldx(n);                     // prefetched; consumed at flush

    auto edge_compute = [&](u32x4 eL, u32x4 eH, u32x2 xw) {
        float m[CPL];
#pragma unroll
        for (int j = 0; j < CPL; ++j) m[j] = bias[j];
#pragma unroll
        for (int k = 0; k < 4; ++k) {
            const h2 ep = __builtin_bit_cast(h2, eL[k]);
#pragma unroll
            for (int j = 0; j < CPL; ++j)
                m[j] = DOT2(ep, __builtin_bit_cast(h2, wlo[j][k]), m[j]);
        }
#pragma unroll
        for (int k = 0; k < 4; ++k) {
            const h2 ep = __builtin_bit_cast(h2, eH[k]);
#pragma unroll
            for (int j = 0; j < CPL; ++j)
                m[j] = DOT2(ep, __builtin_bit_cast(h2, whi[j][k]), m[j]);
        }
#pragma unroll
        for (int j = 0; j < CPL; ++j) {
            const unsigned int word = xw[j >> 1];
            const float xf = __builtin_bit_cast(float,
                (j & 1) ? (word & 0xFFFF0000u) : (word << 16));
            acc[j] += fmaxf(m[j] + xf, 0.0f);
        }
    };
    // flush current node (prefetched xself) + zero-degree ties; prefetch next
    auto adv = [&]() {
        flushv(n, xself); ++n;
        while (n < nend) {
            p1 = __builtin_amdgcn_readfirstlane(off[n + 1]);
            if (p1 != p) { xself = ldx(n); break; }
            flushv(n, ldx(n)); ++n;           // zero-degree tie: immediate (rare)
        }
    };

    // incrementing divergent edge-stream pointers (zd folded into base once)
    const u32x4* pe = (const u32x4*)eas + ((size_t)(p + zd)) * 2;  // 2 u32x4/row
    const int*   ps = ssrc + p + zd;

    // depth-6 pipeline, in-place buffers, runs across node boundaries
    int sA = ps[0], sB = ps[1], sC = ps[2], sD = ps[3], sE = ps[4], sF = ps[5];
    u32x4 eLA = pe[0],  eHA = pe[1];
    u32x4 eLB = pe[2],  eHB = pe[3];
    u32x4 eLC = pe[4],  eHC = pe[5];
    u32x4 eLD = pe[6],  eHD = pe[7];
    u32x4 eLE = pe[8],  eHE = pe[9];
    u32x4 eLF = pe[10], eHF = pe[11];
    u32x2 xA = ldx(sA), xB = ldx(sB), xC = ldx(sC);
    u32x2 xD = ldx(sD), xE = ldx(sE), xF = ldx(sF);
    sA = ps[6]; sB = ps[7]; sC = ps[8]; sD = ps[9]; sE = ps[10]; sF = ps[11];

    for (;;) {
        edge_compute(eLA, eHA, xA);
        eLA = pe[12]; eHA = pe[13]; xA = ldx(sA); sA = ps[12];
        pe += 2; ++ps;
        ++p; if (p == p1) adv();
        if (p >= pend) break;

        edge_compute(eLB, eHB, xB);
        eLB = pe[12]; eHB = pe[13]; xB = ldx(sB); sB = ps[12];
        pe += 2; ++ps;
        ++p; if (p == p1) adv();
        if (p >= pend) break;

        edge_compute(eLC, eHC, xC);
        eLC = pe[12]; eHC = pe[13]; xC = ldx(sC); sC = ps[12];
        pe += 2; ++ps;
        ++p; if (p == p1) adv();
        if (p >= pend) break;

        edge_compute(eLD, eHD, xD);
        eLD = pe[12]; eHD = pe[13]; xD = ldx(sD); sD = ps[12];
        pe += 2; ++ps;
        ++p; if (p == p1) adv();
        if (p >= pend) break;

        edge_compute(eLE, eHE, xE);
        eLE = pe[12]; eHE = pe[13]; xE = ldx(sE); sE = ps[12];
        pe += 2; ++ps;
        ++p; if (p == p1) adv();
        if (p >= pend) break;

        edge_compute(eLF, eHF, xF);
        eLF = pe[12]; eHF = pe[13]; xF = ldx(sF); sF = ps[12];
        pe += 2; ++ps;
        ++p; if (p == p1) adv();
        if (p >= pend) break;
    }
    // safety: trailing zero-degree nodes (normally handled by adv)
    while (n < nend) { flushv(n, ldx(n)); ++n; }
}

// ---------------------------------------------------------------------------
// gemm_fused v4 — BM 64->32. R18 ledger: each fused GEMM ~62 us against
// ~1 us MFMA + ~5 us traffic = latency-exposed; geometry says why: 313
// blocks x 2-blocks/CU capacity -> 199 of 256 CUs host ONE 8-wave block
// (2 waves/SIMD). BM=32: 626 blocks, LDS 64->32 KB, every CU >=2 blocks
// (4 waves/SIMD) through the main phase. Mechanical: ch loops 4->2, acc
// [4]->[2], grid x2. launch_bounds(512,4) kept (R15: min-waves = reg cap).
// ---------------------------------------------------------------------------
template<int K>
__global__ __launch_bounds__(512, 4) void gemm_fused(
    const unsigned short* __restrict__ A,    // [M_PAD, K] (u)
    const unsigned short* __restrict__ WaF,  // frag-packed Wa (g,c,half,lane)
    const float* __restrict__ ba,
    const float* __restrict__ gsc, const float* __restrict__ bsh,
    const unsigned short* __restrict__ WbF,  // frag-packed Wb
    const float* __restrict__ bb,
    unsigned short* __restrict__ out)        // [M_PAD, 256] (h)
{
    constexpr int KC1 = K / 32;              // stage1 k-chunks: 4 or 8
    constexpr int KC2 = H / 32;              // stage2 k-chunks: 8
    constexpr int SLOTS = K / 8;             // 16B slots per A row
    constexpr int CH = BM / 16;              // row chunks: 2
    __shared__ unsigned short Al[BM * K];    // 8/16 KB
    __shared__ unsigned short Tl[BM * H];    // 16 KB, swizzled slots

    const int w = threadIdx.x >> 6, lane = threadIdx.x & 63;
    const int lm = lane & 15, lq = lane >> 4;
    const int n0 = w * 32;                   // this wave's 32 output cols
    const int m0 = blockIdx.x * BM;

    const bf16x8* Wa8 = (const bf16x8*)WaF;
    const bf16x8* Wb8 = (const bf16x8*)WbF;

    // cooperative A-tile stage (512 threads), XOR-swizzled 16B slots
#pragma unroll
    for (int i = 0; i < BM * SLOTS / 512; ++i) {
        const int t = i * 512 + threadIdx.x;
        const int row = t / SLOTS, slot = t % SLOTS;
        const uint4 v = *(const uint4*)(A + (size_t)(m0 + row) * K + slot * 8);
        *(uint4*)((char*)Al + row * (K * 2) + ((slot ^ (row & 7)) * 16)) = v;
    }

    const float inv = rsqrtf(1.0f + 1e-5f);
    const float bc0 = ba[n0 + lm],  bc1 = ba[n0 + 16 + lm];
    const float gc0 = gsc[n0 + lm], gc1 = gsc[n0 + 16 + lm];
    const float sc0 = bsh[n0 + lm], sc1 = bsh[n0 + 16 + lm];

    __syncthreads();

    // ---- stage 1: t = relu((u@Wa^T + ba)*inv*g + bt) -> LDS (half-K passes)
    {
        f32x4 acc0[CH], acc1[CH];
#pragma unroll
        for (int ch = 0; ch < CH; ++ch) {
            acc0[ch] = (f32x4){0.f, 0.f, 0.f, 0.f};
            acc1[ch] = (f32x4){0.f, 0.f, 0.f, 0.f};
        }
#pragma unroll
        for (int kh = 0; kh < KC1; kh += 4) {
            bf16x8 C0[4], C1[4];
#pragma unroll
            for (int c = 0; c < 4; ++c) {
                const int fi = (w * KC1 + kh + c) * 2;
                C0[c] = Wa8[(size_t)(fi + 0) * 64 + lane];
                C1[c] = Wa8[(size_t)(fi + 1) * 64 + lane];
            }
#pragma unroll
            for (int ch = 0; ch < CH; ++ch) {
                const int row = ch * 16 + lm;
                const char* rbase = (const char*)Al + row * (K * 2);
#pragma unroll
                for (int c = 0; c < 4; ++c) {
                    const int slot = (lq + (kh + c) * 4) ^ (row & 7);
                    const bf16x8 a = *(const bf16x8*)(rbase + slot * 16);
                    acc0[ch] = __builtin_amdgcn_mfma_f32_16x16x32_bf16(a, C0[c], acc0[ch], 0, 0, 0);
                    acc1[ch] = __builtin_amdgcn_mfma_f32_16x16x32_bf16(a, C1[c], acc1[ch], 0, 0, 0);
                }
            }
        }
        // write t tile to LDS (bf16, swizzled slots)
#pragma unroll
        for (int ch = 0; ch < CH; ++ch) {
#pragma unroll
            for (int r = 0; r < 4; ++r) {
                const int rowo = ch * 16 + lq * 4 + r;
                const float v0 = fmaxf((acc0[ch][r] + bc0) * inv * gc0 + sc0, 0.0f);
                const float v1 = fmaxf((acc1[ch][r] + bc1) * inv * gc1 + sc1, 0.0f);
                const int col0 = n0 + lm, col1 = n0 + 16 + lm;
                *(unsigned short*)((char*)Tl + rowo * (H * 2)
                    + (((col0 >> 3) ^ (rowo & 7)) << 4) + ((col0 & 7) << 1)) = f2bf(v0);
                *(unsigned short*)((char*)Tl + rowo * (H * 2)
                    + (((col1 >> 3) ^ (rowo & 7)) << 4) + ((col1 & 7) << 1)) = f2bf(v1);
            }
        }
    }

    const float eb0 = bb[n0 + lm], eb1 = bb[n0 + 16 + lm];

    __syncthreads();

    // ---- stage 2: h = relu(t @ Wb^T + bb) (half-K passes)
    {
        f32x4 acc0[CH], acc1[CH];
#pragma unroll
        for (int ch = 0; ch < CH; ++ch) {
            acc0[ch] = (f32x4){0.f, 0.f, 0.f, 0.f};
            acc1[ch] = (f32x4){0.f, 0.f, 0.f, 0.f};
        }
#pragma unroll
        for (int kh = 0; kh < KC2; kh += 4) {
            bf16x8 C0[4], C1[4];
#pragma unroll
            for (int c = 0; c < 4; ++c) {
                const int fi = (w * KC2 + kh + c) * 2;
                C0[c] = Wb8[(size_t)(fi + 0) * 64 + lane];
                C1[c] = Wb8[(size_t)(fi + 1) * 64 + lane];
            }
#pragma unroll
            for (int ch = 0; ch < CH; ++ch) {
                const int row = ch * 16 + lm;
                const char* rbase = (const char*)Tl + row * (H * 2);
#pragma unroll
                for (int c = 0; c < 4; ++c) {
                    const int slot = (lq + (kh + c) * 4) ^ (row & 7);
                    const bf16x8 a = *(const bf16x8*)(rbase + slot * 16);
                    acc0[ch] = __builtin_amdgcn_mfma_f32_16x16x32_bf16(a, C0[c], acc0[ch], 0, 0, 0);
                    acc1[ch] = __builtin_amdgcn_mfma_f32_16x16x32_bf16(a, C1[c], acc1[ch], 0, 0, 0);
                }
            }
        }
#pragma unroll
        for (int ch = 0; ch < CH; ++ch) {
            const int mr = m0 + ch * 16;
#pragma unroll
            for (int r = 0; r < 4; ++r) {
                const int rowo = mr + lq * 4 + r;
                if (rowo >= N_NODES) continue;
                const float v0 = fmaxf(acc0[ch][r] + eb0, 0.0f);
                const float v1 = fmaxf(acc1[ch][r] + eb1, 0.0f);
                out[(size_t)rowo * H + n0 + lm]      = f2bf(v0);
                out[(size_t)rowo * H + n0 + 16 + lm] = f2bf(v1);
            }
        }
    }
}

// ---------------------------------------------------------------------------
// pool2 v2 (R13 win): u32x4 vectorized loads, 8 rows in flight, LDS
// cross-rowgroup reduce, one atomic per column.
// ---------------------------------------------------------------------------
#define RSPLIT 6
__global__ __launch_bounds__(256) void pool2(
    const unsigned short* __restrict__ h1, const unsigned short* __restrict__ h2,
    const unsigned short* __restrict__ h3, const int* __restrict__ start,
    float* __restrict__ pool)
{
    const int g = blockIdx.x & 63, layer = blockIdx.x >> 6;
    const unsigned short* h = (layer == 0) ? h1 : (layer == 1) ? h2 : h3;
    const int r0 = start[g], r1 = start[g + 1];
    const int nr = r1 - r0;
    if (nr <= 0) return;
    const int chunk = (nr + RSPLIT - 1) / RSPLIT;
    const int rs = r0 + blockIdx.y * chunk;
    const int re = (rs + chunk < r1) ? rs + chunk : r1;
    if (rs >= re) return;

    const int cg = threadIdx.x & 31;         // cols cg*8 .. cg*8+7
    const int rg = threadIdx.x >> 5;         // row group 0..7
    float s0 = 0.f, s1 = 0.f, s2 = 0.f, s3 = 0.f;
    float s4 = 0.f, s5 = 0.f, s6 = 0.f, s7 = 0.f;
    for (int r = rs + rg; r < re; r += 8) {
        const u32x4 v = *(const u32x4*)(h + (size_t)r * H + cg * 8);
        s0 += __builtin_bit_cast(float, v[0] << 16);
        s1 += __builtin_bit_cast(float, v[0] & 0xFFFF0000u);
        s2 += __builtin_bit_cast(float, v[1] << 16);
        s3 += __builtin_bit_cast(float, v[1] & 0xFFFF0000u);
        s4 += __builtin_bit_cast(float, v[2] << 16);
        s5 += __builtin_bit_cast(float, v[2] & 0xFFFF0000u);
        s6 += __builtin_bit_cast(float, v[3] << 16);
        s7 += __builtin_bit_cast(float, v[3] & 0xFFFF0000u);
    }
    __shared__ float red[8][256];
    red[rg][cg * 8 + 0] = s0; red[rg][cg * 8 + 1] = s1;
    red[rg][cg * 8 + 2] = s2; red[rg][cg * 8 + 3] = s3;
    red[rg][cg * 8 + 4] = s4; red[rg][cg * 8 + 5] = s5;
    red[rg][cg * 8 + 6] = s6; red[rg][cg * 8 + 7] = s7;
    __syncthreads();
    float t = 0.f;
#pragma unroll
    for (int q = 0; q < 8; ++q) t += red[q][threadIdx.x];
    atomicAdd(&pool[(size_t)g * POOL_W + layer * 256 + threadIdx.x], t);
}

// ---------------------------------------------------------------------------
// fc_head v3 (R13 win): two graphs per block — each L1w fragment loaded once
// and dotted against both p-vectors. Grid (32, 12).
// ---------------------------------------------------------------------------
__global__ __launch_bounds__(256) void fc_head(
    const float* __restrict__ pool, const int* __restrict__ start,
    const float* __restrict__ L1w, const float* __restrict__ L1b,
    const float* __restrict__ L2w, float* __restrict__ gsum)
{
    const int g0 = blockIdx.x * 2, g1 = g0 + 1;
    __shared__ float p[2][POOL_W];

    const float rc0 = 1.0f / fmaxf((float)(start[g0 + 1] - start[g0]), 1.0f);
    const float rc1 = 1.0f / fmaxf((float)(start[g1 + 1] - start[g1]), 1.0f);
    for (int i = threadIdx.x; i < POOL_W; i += 256) {
        p[0][i] = pool[(size_t)g0 * POOL_W + i] * rc0;
        p[1][i] = pool[(size_t)g1 * POOL_W + i] * rc1;
    }
    __syncthreads();

    const int wv = threadIdx.x >> 6, lane = threadIdx.x & 63;
    const float4* pA = (const float4*)p[0];
    const float4* pB = (const float4*)p[1];
    const float4 a0 = pA[lane], a1 = pA[lane + 64], a2 = pA[lane + 128];
    const float4 b0 = pB[lane], b1 = pB[lane + 64], b2 = pB[lane + 128];

    const int ob = blockIdx.y * 64 + wv * 16;
    float part0 = 0.0f, part1 = 0.0f;
#pragma unroll 4
    for (int t = 0; t < 16; ++t) {
        const int o = ob + t;
        const float4* wr = (const float4*)(L1w + (size_t)o * POOL_W);
        const float4 wa = wr[lane], wb = wr[lane + 64], wc = wr[lane + 128];
        float accA = wa.x * a0.x + wa.y * a0.y + wa.z * a0.z + wa.w * a0.w
                   + wb.x * a1.x + wb.y * a1.y + wb.z * a1.z + wb.w * a1.w
                   + wc.x * a2.x + wc.y * a2.y + wc.z * a2.z + wc.w * a2.w;
        float accB = wa.x * b0.x + wa.y * b0.y + wa.z * b0.z + wa.w * b0.w
                   + wb.x * b1.x + wb.y * b1.y + wb.z * b1.z + wb.w * b1.w
                   + wc.x * b2.x + wc.y * b2.y + wc.z * b2.z + wc.w * b2.w;
#pragma unroll
        for (int off = 32; off > 0; off >>= 1) {
            accA += __shfl_xor(accA, off);
            accB += __shfl_xor(accB, off);
        }
        if (lane == 0) {
            const float r = fmaxf(accA + L1b[o], 0.0f);
            const float s = fmaxf(accB + L1b[o], 0.0f);
            part0 += r * L2w[o];
            part1 += s * L2w[o];
        }
    }
    if (lane == 0) {
        atomicAdd(&gsum[g0], part0);
        atomicAdd(&gsum[g1], part1);
    }
}

__global__ __launch_bounds__(64) void sig_kernel(
    const float* __restrict__ gsum, const float* __restrict__ L2b,
    float* __restrict__ out)
{
    const int g = threadIdx.x;
    if (g < N_GRAPHS) out[g] = 1.0f / (1.0f + expf(-(gsum[g] + L2b[0])));
}

// ---------------------------------------------------------------------------
extern "C" void kernel_launch(void* const* d_in, const int* in_sizes, int n_in,
                              void* d_out, int out_size, void* d_ws, size_t ws_size,
                              hipStream_t stream)
{
    const float* x     = (const float*)d_in[0];
    const float* ea    = (const float*)d_in[1];
    const int*   src   = (const int*)d_in[2];
    const int*   dst   = (const int*)d_in[3];
    const int*   batch = (const int*)d_in[4];

    const float* We[3]; const float* be[3]; const float* Wa[3]; const float* ba[3];
    const float* gg[3]; const float* bt[3]; const float* Wb[3]; const float* bb[3];
    for (int l = 0; l < 3; ++l) {
        const int o = 5 + 8 * l;
        We[l] = (const float*)d_in[o + 0]; be[l] = (const float*)d_in[o + 1];
        Wa[l] = (const float*)d_in[o + 2]; ba[l] = (const float*)d_in[o + 3];
        gg[l] = (const float*)d_in[o + 4]; bt[l] = (const float*)d_in[o + 5];
        Wb[l] = (const float*)d_in[o + 6]; bb[l] = (const float*)d_in[o + 7];
    }
    const float* L1w = (const float*)d_in[29];
    const float* L1b = (const float*)d_in[30];
    const float* L2w = (const float*)d_in[31];
    const float* L2b = (const float*)d_in[32];

    // ---- workspace layout ----
    float* pool   = (float*)d_ws;                              // 64*768
    float* gsum   = pool + (size_t)N_GRAPHS * POOL_W;          // 64 (zeroed with pool)
    int*   deg    = (int*)(gsum + N_GRAPHS);                   // N
    int*   off    = deg + N_NODES;                             // N+1
    int*   cursor = off + N_NODES + 1;                         // N
    int*   start  = cursor + N_NODES;                          // 72
    int*   cmap   = start + 72;                                // NCHUNK+1
    int*   ssrc   = (int*)((((uintptr_t)(cmap + NCHUNK + 1)) + 31) & ~(uintptr_t)31);  // E+16 ints, CSR
    unsigned short* eas = (unsigned short*)((((uintptr_t)(ssrc + N_EDGES + 16)) + 31) & ~(uintptr_t)31); // [E+16,16] f16 CSR
    unsigned short* xb = (unsigned short*)((((uintptr_t)(eas + (size_t)(N_EDGES + 16) * 16)) + 31) & ~(uintptr_t)31);
    unsigned short* u  = xb + (size_t)M_PAD * DIN;             // [M_PAD,256] (layer1 uses 128)
    unsigned short* h1 = u  + (size_t)M_PAD * H;
    unsigned short* h2 = h1 + (size_t)M_PAD * H;
    unsigned short* h3 = h2 + (size_t)M_PAD * H;
    unsigned short* wbf[6];
    wbf[0] = h3 + (size_t)M_PAD * H;                           // Wa1 frag [256,128]
    wbf[1] = wbf[0] + H * DIN;
    for (int i = 2; i < 6; ++i) wbf[i] = wbf[i - 1] + H * H;
    unsigned short* weh[3];
    weh[0] = wbf[5] + H * H;                                   // We1 [128,16] f16
    weh[1] = weh[0] + DIN * 16;                                // We2 [256,16] f16
    weh[2] = weh[1] + H * 16;                                  // We3 [256,16] f16

    // batched converts + deg/pool+gsum zeroing in one launch (12 jobs)
    CvtJobs jobs;
    jobs.j[0]  = { x,       xb,                    N_NODES * DIN / 4,       0, 0 };
    jobs.j[1]  = { Wa[0],   wbf[0],                H * DIN / 8,             3, DIN };
    jobs.j[2]  = { Wb[0],   wbf[1],                H * H / 8,               3, H };
    jobs.j[3]  = { Wa[1],   wbf[2],                H * H / 8,               3, H };
    jobs.j[4]  = { Wb[1],   wbf[3],                H * H / 8,               3, H };
    jobs.j[5]  = { Wa[2],   wbf[4],                H * H / 8,               3, H };
    jobs.j[6]  = { Wb[2],   wbf[5],                H * H / 8,               3, H };
    jobs.j[7]  = { nullptr, (unsigned short*)deg,  N_NODES * 4 / 8,         2, 0 };  // zero N ints
    jobs.j[8]  = { nullptr, (unsigned short*)pool, (N_GRAPHS * POOL_W + N_GRAPHS) * 4 / 8, 2, 0 }; // zero pool+gsum
    jobs.j[9]  = { We[0],   weh[0],                DIN * 16 / 4,            1, 0 };
    jobs.j[10] = { We[1],   weh[1],                H * 16 / 4,              1, 0 };
    jobs.j[11] = { We[2],   weh[2],                H * 16 / 4,              1, 0 };
    cvt_all<<<dim3(320, 12), 256, 0, stream>>>(jobs);

    // CSR + graph boundaries; scatter also computes chunk map + ssrc pad
    hist_kernel<<<EDGE_BLOCKS, 256, 0, stream>>>(dst, deg);
    scan_kernel<<<1, 1024, 0, stream>>>(deg, off, cursor, batch, start);
    scatter_kernel<<<EDGE_BLOCKS + CMAP_BLOCKS, 256, 0, stream>>>(
        src, dst, ea, cursor, ssrc, eas, off, cmap);

    const int agrid = NCHUNK / 4;               // agg3: 1 chunk/wave, 4 waves/block
    const int ggrid = M_PAD / BM;               // gemm_fused: 626 blocks x 512

    // ---- layer 1 (in=128) ----
    agg3<DIN><<<agrid, 256, 0, stream>>>(xb, eas, ssrc, off, cmap, weh[0], be[0], u);
    gemm_fused<DIN><<<ggrid, 512, 0, stream>>>(u, wbf[0], ba[0], gg[0], bt[0], wbf[1], bb[0], h1);
    // ---- layer 2 ----
    agg3<H><<<agrid, 256, 0, stream>>>(h1, eas, ssrc, off, cmap, weh[1], be[1], u);
    gemm_fused<H><<<ggrid, 512, 0, stream>>>(u, wbf[2], ba[1], gg[1], bt[1], wbf[3], bb[1], h2);
    // ---- layer 3 ----
    agg3<H><<<agrid, 256, 0, stream>>>(h2, eas, ssrc, off, cmap, weh[2], be[2], u);
    gemm_fused<H><<<ggrid, 512, 0, stream>>>(u, wbf[4], ba[2], gg[2], bt[2], wbf[5], bb[2], h3);

    // parallel mean-pool + head (fc_head: 2 graphs/block)
    pool2<<<dim3(3 * N_GRAPHS, RSPLIT), 256, 0, stream>>>(h1, h2, h3, start, pool);
    fc_head<<<dim3(N_GRAPHS / 2, POOL_W / 64), 256, 0, stream>>>(pool, start, L1w, L1b, L2w, gsum);
    sig_kernel<<<1, 64, 0, stream>>>(gsum, L2b, (float*)d_out);
}